// Round 11
// baseline (254.107 us; speedup 1.0000x reference)
//
#include <hip/hip_runtime.h>
#include <hip/hip_bf16.h>
#include <stdint.h>

#define NB 4
#define NS 2048
#define ND 1024
#define NH 16
#define NHS 64
#define NEG_BIG (-1e30f)
// 1/sqrt(HS) * log2(e): folds softmax exp->exp2 into Q scaling (exactly softmax-invariant)
#define Q_SCALE 0.18033688011112042f

typedef __bf16 bf16x8 __attribute__((ext_vector_type(8)));
typedef float floatx4 __attribute__((ext_vector_type(4)));
typedef short s16x4 __attribute__((ext_vector_type(4)));

#if defined(__has_builtin)
#if __has_builtin(__builtin_amdgcn_mfma_f32_16x16x16bf16_1k)
#define HAVE_MFMA1K 1
#endif
#endif
#ifndef HAVE_MFMA1K
#define HAVE_MFMA1K 0
#endif

static constexpr size_t WSLAB = (size_t)NH * ND * NHS;        // 2^20 elems per weight mat
static constexpr size_t QSLAB = (size_t)NB * NH * NS * NHS;   // 8M elems per QKV/Y slab
static constexpr size_t XSLAB = (size_t)NB * NS * ND;         // 8M elems (x as bf16)

__device__ __forceinline__ uint16_t f2b(float f) {
    union { __hip_bfloat16 h; uint16_t u; } cv;
    cv.h = __float2bfloat16(f);
    return cv.u;
}

// async global->LDS, 16B per lane. LDS dest = wave-uniform base + lane*16 (UNPADDED only).
__device__ __forceinline__ void gll16(const void* g, void* l) {
  __builtin_amdgcn_global_load_lds(
      (__attribute__((address_space(1))) void*)(uintptr_t)g,
      (__attribute__((address_space(3))) void*)(uintptr_t)l,
      16, 0, 0);
}

// ---------------- kernel P: merged x-convert + weight convert/transpose ----------------
__global__ __launch_bounds__(256) void k_prep(
    const float* __restrict__ x, const float* __restrict__ Wq,
    const float* __restrict__ Wk, const float* __restrict__ Wv,
    const float* __restrict__ Wo, uint16_t* __restrict__ xb,
    uint16_t* __restrict__ wt) {
  __shared__ __align__(16) uint16_t T[64][72];
  int bid = blockIdx.x;
  int tid = threadIdx.x;
  if (bid < 4096) {
    size_t i0 = ((size_t)bid * 256 + tid) * 8;
    float4 f0 = *(const float4*)&x[i0];
    float4 f1 = *(const float4*)&x[i0 + 4];
    __align__(16) uint16_t tmp[8];
    tmp[0] = f2b(f0.x); tmp[1] = f2b(f0.y); tmp[2] = f2b(f0.z); tmp[3] = f2b(f0.w);
    tmp[4] = f2b(f1.x); tmp[5] = f2b(f1.y); tmp[6] = f2b(f1.z); tmp[7] = f2b(f1.w);
    *(uint4*)&xb[i0] = *(uint4*)tmp;
    return;
  }
  bid -= 4096;
  const float* src; uint16_t* dst;
  int srcStride, dstStride, r0, c0;
  if (bid < 768) {
    int mat = bid >> 8;
    int rem = bid & 255;
    int h = rem >> 4, dt = rem & 15;
    const float* W = (mat == 0) ? Wq : (mat == 1) ? Wk : Wv;
    src = W + (size_t)h * (ND * NHS);
    dst = wt + (size_t)mat * WSLAB + (size_t)h * (NHS * ND);
    srcStride = NHS; dstStride = ND;
    r0 = dt * 64; c0 = 0;
  } else {
    int rem = bid - 768;
    int dt = rem >> 4, et = rem & 15;
    src = Wo; dst = wt + 3 * WSLAB;
    srcStride = ND; dstStride = ND;
    r0 = dt * 64; c0 = et * 64;
  }
  for (int u = tid; u < 1024; u += 256) {
    int row = u >> 4, cq = u & 15;
    float4 f = *(const float4*)&src[(size_t)(r0 + row) * srcStride + c0 + cq * 4];
    uint16_t* p = &T[row][cq * 4];
    p[0] = f2b(f.x); p[1] = f2b(f.y); p[2] = f2b(f.z); p[3] = f2b(f.w);
  }
  __syncthreads();
  for (int u = tid; u < 512; u += 256) {
    int c = u >> 3, cg = u & 7;
    __align__(16) uint16_t tmp[8];
    for (int j = 0; j < 8; j++) tmp[j] = T[cg * 8 + j][c];
    *(uint4*)&dst[(size_t)(c0 + c) * dstStride + r0 + cg * 8] = *(uint4*)tmp;
  }
}

// ---------------- kernel 1: fused QKV GEMM, 128x128 2-phase, 2 blocks/CU + T2 swizzle ----
// LOCKED (round 10): five structures measured 70.7-77.3us (~700-730 TF, 28-31% MfmaUtil):
// 256²-8slot (77.3), 256²-4slot (74.0), 128x256-packed (73.8), THIS (70.7, best),
// 256x128-counted-vmcnt/144KB (71.5, 1 blk/CU). The 2-phase stage+vmcnt+barrier critical
// path is the plateau; partial T3/T4 embodiments revert to it, and the full 8-phase
// co-design hit L2-thrash (r1) / occupancy (r10) walls on this K=1024 3-matrix shape.
// Do not re-trade without a fundamentally different schedule.
__global__ __launch_bounds__(512, 4) void k_qkv(
    const uint16_t* __restrict__ xb, const uint16_t* __restrict__ wt,
    uint16_t* __restrict__ qk, uint16_t* __restrict__ vt) {
  __shared__ __align__(16) uint16_t L[32768];   // 64 KB

  int bid = blockIdx.x;
  int xcd = bid & 7, idx = bid >> 3;     // 192 tiles per XCD chunk
  int mtile = xcd * 8 + (idx & 7);       // 8 m-tiles per XCD, inner (2MB A L2-resident)
  int ntile = idx >> 3;                  // 24 n-tiles, outer
  int m0 = mtile * 128;
  int n0 = ntile * 128;

  int tid = threadIdx.x;
  int wave = tid >> 6, lane = tid & 63, quad = lane >> 4, l16 = lane & 15;
  int wr = wave >> 2, wc = wave & 3;

  // staging: thread covers (row = tid>>2, chunk = tid&3) of a 128x32 half.
  // T2 pre-swizzle of the GLOBAL source chunk: key = (row>>2)&3 = (tid>>4)&3.
  int swc = ((tid & 3) ^ ((tid >> 4) & 3)) * 8;
  const uint16_t* pA = xb + (size_t)(m0 + (tid >> 2)) * ND + swc;
  const uint16_t* pB = wt + (size_t)(n0 + (tid >> 2)) * ND + swc;
  const int stOff = wave * 512;          // wave-uniform LDS stage base (u16)

  // frag-read bases (u16 within a slot); chunk XOR'd with the same key
  const int rq = (quad ^ (l16 >> 2)) * 8;
  const int offA = (wr * 64 + l16) * 32 + rq;
  const int offB = (wc * 32 + l16) * 32 + rq;

  floatx4 acc[4][2];
  #pragma unroll
  for (int i = 0; i < 4; i++)
    #pragma unroll
    for (int j = 0; j < 2; j++) acc[i][j] = (floatx4){0.f, 0.f, 0.f, 0.f};

#define STAGE(A_)                                                               \
  do {                                                                          \
    int a_ = (A_);                                                              \
    if (a_ < 32) {                                                              \
      int ko_ = (a_ >> 1) * 64 + (a_ & 1) * 32;                                 \
      gll16(pA + ko_, &L[(a_ & 3) * 4096 + stOff]);                             \
      gll16(pB + ko_, &L[16384 + (a_ & 3) * 4096 + stOff]);                     \
    }                                                                           \
  } while (0)

#define PH_BAR()                         \
  do {                                   \
    asm volatile("" ::: "memory");       \
    __builtin_amdgcn_s_barrier();        \
    asm volatile("" ::: "memory");       \
  } while (0)

  // prologue: lo(0), hi(0), lo(1); drain until lo(0) landed (4 newer loads in flight)
  STAGE(0); STAGE(1); STAGE(2);
  asm volatile("s_waitcnt vmcnt(4)" ::: "memory");
  PH_BAR();

#define MFMA8()                                                                           \
  _Pragma("unroll")                                                                       \
  for (int mt_ = 0; mt_ < 4; mt_++)                                                       \
    _Pragma("unroll")                                                                     \
    for (int nt_ = 0; nt_ < 2; nt_++)                                                     \
      acc[mt_][nt_] = __builtin_amdgcn_mfma_f32_16x16x32_bf16(af[mt_], bfr[nt_], acc[mt_][nt_], 0, 0, 0)

  for (int t = 0; t < 16; ++t) {
    {
      // ---- ph0: read lo(t) [slot (2t)&3], stage hi(t+1) ----
      int sA = ((2 * t) & 3) * 4096;
      int sB = 16384 + ((2 * t) & 3) * 4096;
      bf16x8 af[4], bfr[2];
      #pragma unroll
      for (int i = 0; i < 4; i++) af[i] = *(const bf16x8*)&L[sA + offA + i * 512];
      #pragma unroll
      for (int i = 0; i < 2; i++) bfr[i] = *(const bf16x8*)&L[sB + offB + i * 512];
      STAGE(2 * t + 3);
      PH_BAR();
      __builtin_amdgcn_s_setprio(1);
      MFMA8();
      __builtin_amdgcn_s_setprio(0);
      if (t < 15) { asm volatile("s_waitcnt vmcnt(4)" ::: "memory"); }
      else        { asm volatile("s_waitcnt vmcnt(0)" ::: "memory"); }
      PH_BAR();
    }
    {
      // ---- ph1: read hi(t) [slot (2t+1)&3], stage lo(t+2) ----
      int sA = ((2 * t + 1) & 3) * 4096;
      int sB = 16384 + ((2 * t + 1) & 3) * 4096;
      bf16x8 af[4], bfr[2];
      #pragma unroll
      for (int i = 0; i < 4; i++) af[i] = *(const bf16x8*)&L[sA + offA + i * 512];
      #pragma unroll
      for (int i = 0; i < 2; i++) bfr[i] = *(const bf16x8*)&L[sB + offB + i * 512];
      STAGE(2 * t + 4);
      PH_BAR();
      __builtin_amdgcn_s_setprio(1);
      MFMA8();
      __builtin_amdgcn_s_setprio(0);
      if (t < 14)       { asm volatile("s_waitcnt vmcnt(4)" ::: "memory"); }
      else if (t == 14) { asm volatile("s_waitcnt vmcnt(2)" ::: "memory"); }
      if (t < 15) PH_BAR();
    }
  }
#undef MFMA8
#undef STAGE
#undef PH_BAR

  // n-decomposition: head hh, element e within head
  int matid = n0 >> 10;
  int b = m0 >> 11;
  if (matid == 2) {
    // ---- V blocks: store V^T ([b,h,e,s]) directly from registers (uint2, s-contiguous) ----
    int hh = ((n0 - 2048) >> 6) + (wc >> 1);
    #pragma unroll
    for (int nt = 0; nt < 2; nt++) {
      int e = (wc & 1) * 32 + nt * 16 + l16;
      uint16_t* vrow = vt + ((size_t)(b * 16 + hh) * 64 + e) * NS;
      #pragma unroll
      for (int mt = 0; mt < 4; mt++) {
        __align__(8) uint16_t t4v[4];
        #pragma unroll
        for (int r = 0; r < 4; r++) t4v[r] = f2b(acc[mt][nt][r]);
        int s = (m0 & 2047) + wr * 64 + mt * 16 + quad * 4;
        *(uint2*)&vrow[s] = *(uint2*)t4v;
      }
    }
  } else {
    // ---- Q/K blocks: scatter to [b,h,s,e] with Q pre-scale ----
    float scale = (matid == 0) ? Q_SCALE : 1.0f;
    uint16_t* base = qk + (size_t)matid * QSLAB;
    int hh = ((n0 & 1023) >> 6) + (wc >> 1);
    #pragma unroll
    for (int mt = 0; mt < 4; mt++) {
      int s = (m0 & 2047) + wr * 64 + mt * 16 + quad * 4;
      size_t rbase = ((size_t)(b * 16 + hh) * NS + s) * NHS;
      #pragma unroll
      for (int nt = 0; nt < 2; nt++)
        #pragma unroll
        for (int r = 0; r < 4; r++)
          base[rbase + (size_t)r * NHS + (wc & 1) * 32 + nt * 16 + l16] =
              f2b(acc[mt][nt][r] * scale);
    }
  }
}

#if HAVE_MFMA1K
// ---------------- kernel 2: causal attention, S^T trick, gll16 staging, 1 barrier/step --
// (round-9 verified best: gll16 2-buffer ring, one __syncthreads/step, both-sides
// swizzle; VGPR-neutral vs reg-prefetch. Keep.)
__global__ __launch_bounds__(256, 4) void k_attn(
    const uint16_t* __restrict__ Q, const uint16_t* __restrict__ K,
    const uint16_t* __restrict__ VT, uint16_t* __restrict__ Y) {
  __shared__ __align__(16) uint16_t Ks[2][4096];   // [buf][k*64 + swz e-chunk]
  __shared__ __align__(16) uint16_t Vs[2][4096];   // [buf][e*64 + swz key-chunk]
  int bh = blockIdx.y;
  int b = bh >> 4, h = bh & 15;
  int ta = blockIdx.x;       // 0..15
  int tb = 31 - ta;          // 16..31
  const uint16_t* Qp = Q + (size_t)bh * (NS * NHS);
  const uint16_t* Kp = K + (size_t)bh * (NS * NHS);
  const uint16_t* Vp = VT + (size_t)bh * (NS * NHS);  // [e][key]
  int tid = threadIdx.x;
  int wv = tid >> 6, lane = tid & 63, quad = lane >> 4, l16 = lane & 15;

  // gll16 staging map: wave wv covers rows [wv*16, wv*16+16) in two 8-row groups.
  int srow = lane >> 3;                       // row offset in 8-row group (= row&7)
  int swOff = ((lane & 7) ^ srow) * 8;        // pre-swizzled source chunk (u16)
  int stRow0 = wv * 16 + srow;
  int stRow1 = wv * 16 + 8 + srow;
  const int dst0 = wv * 1024;                 // wave-uniform LDS dest (u16)
  const int dst1 = wv * 1024 + 512;

#define STAGE_KV(KT, BUF)                                                         \
  do {                                                                            \
    int kt_ = (KT);                                                               \
    gll16(Kp + (size_t)(kt_ * 64 + stRow0) * NHS + swOff, &Ks[BUF][dst0]);        \
    gll16(Kp + (size_t)(kt_ * 64 + stRow1) * NHS + swOff, &Ks[BUF][dst1]);        \
    gll16(Vp + (size_t)stRow0 * NS + kt_ * 64 + swOff, &Vs[BUF][dst0]);           \
    gll16(Vp + (size_t)stRow1 * NS + kt_ * 64 + swOff, &Vs[BUF][dst1]);           \
  } while (0)

  // swizzled frag-read column offsets (u16 within a 64-u16 row)
  int e3 = l16 & 7;
  int kc0 = (quad ^ e3) * 8;              // kb0: logical chunk quad
  int kc1 = ((4 | quad) ^ e3) * 8;        // kb1: logical chunk 4+quad
  int vql = (quad & 1) * 4;
  int vqh = quad >> 1;
  int vcol[4];
  #pragma unroll
  for (int ct = 0; ct < 4; ct++)
    vcol[ct] = (((ct * 2 + vqh) ^ e3) * 8) + vql;

  // Q fragments from global; B operand of S^T = K.Q^T (n = q-row = l16)
  int rA = ta * 64 + wv * 16 + l16;
  int rB = tb * 64 + wv * 16 + l16;
  bf16x8 aqA0 = *(const bf16x8*)&Qp[(size_t)rA * NHS + quad * 8];
  bf16x8 aqA1 = *(const bf16x8*)&Qp[(size_t)rA * NHS + 32 + quad * 8];
  bf16x8 aqB0 = *(const bf16x8*)&Qp[(size_t)rB * NHS + quad * 8];
  bf16x8 aqB1 = *(const bf16x8*)&Qp[(size_t)rB * NHS + 32 + quad * 8];

  float lAs = 0.f, lBs = 0.f;          // per-lane row-sum (all p of a lane share q-row l16)
  floatx4 oA[4], oB[4];                // O^T accumulators, one per e-tile
  for (int et = 0; et < 4; et++) {
    oA[et] = (floatx4){0.f, 0.f, 0.f, 0.f};
    oB[et] = (floatx4){0.f, 0.f, 0.f, 0.f};
  }

  // prologue: tile 0 -> buf0; __syncthreads' intrinsic vmcnt(0) waits it (and Q loads)
  STAGE_KV(0, 0);
  __syncthreads();

  for (int kt = 0; kt <= tb; kt++) {
    int cur = kt & 1;
    if (kt < tb) STAGE_KV(kt + 1, cur ^ 1);   // buf^1 free since end-of-step kt-1
    const uint16_t* KB = &Ks[cur][0];
    const uint16_t* VB = &Vs[cur][0];
    bool doA = (kt <= ta);  // uniform across block

    // ---- S^T tiles + mask + exp2 + pack (P^T lands in B-layout of K=16 MFMA) ----
    s16x4 pbA[4], pbB[4];
    #pragma unroll
    for (int ct = 0; ct < 4; ct++) {
      int krow = (ct * 16 + l16) * 64;
      bf16x8 kb0 = *(const bf16x8*)&KB[krow + kc0];
      bf16x8 kb1 = *(const bf16x8*)&KB[krow + kc1];
      int key = kt * 64 + ct * 16 + quad * 4;
      floatx4 c = (floatx4){0.f, 0.f, 0.f, 0.f};
      c = __builtin_amdgcn_mfma_f32_16x16x32_bf16(kb0, aqB0, c, 0, 0, 0);
      c = __builtin_amdgcn_mfma_f32_16x16x32_bf16(kb1, aqB1, c, 0, 0, 0);
      #pragma unroll
      for (int r = 0; r < 4; r++) {
        float s = (kt == tb && key + r > rB) ? NEG_BIG : c[r];
        float p = __builtin_amdgcn_exp2f(s);
        lBs += p;
        pbB[ct][r] = (short)f2b(p);
      }
      if (doA) {
        floatx4 d = (floatx4){0.f, 0.f, 0.f, 0.f};
        d = __builtin_amdgcn_mfma_f32_16x16x32_bf16(kb0, aqA0, d, 0, 0, 0);
        d = __builtin_amdgcn_mfma_f32_16x16x32_bf16(kb1, aqA1, d, 0, 0, 0);
        #pragma unroll
        for (int r = 0; r < 4; r++) {
          float s = (kt == ta && key + r > rA) ? NEG_BIG : d[r];
          float p = __builtin_amdgcn_exp2f(s);
          lAs += p;
          pbA[ct][r] = (short)f2b(p);
        }
      }
    }
    // ---- O^T += V^T . P^T (A-frag = 4 keys of V^T via swizzled 8B reads) ----
    #pragma unroll
    for (int et = 0; et < 4; et++) {
      int vrow = (et * 16 + l16) * 64;
      #pragma unroll
      for (int ct = 0; ct < 4; ct++) {
        s16x4 va = *(const s16x4*)&VB[vrow + vcol[ct]];
        oB[et] = __builtin_amdgcn_mfma_f32_16x16x16bf16_1k(va, pbB[ct], oB[et], 0, 0, 0);
        if (doA)
          oA[et] = __builtin_amdgcn_mfma_f32_16x16x16bf16_1k(va, pbA[ct], oA[et], 0, 0, 0);
      }
    }
    __syncthreads();   // publishes buf^1 gll16s (intrinsic vmcnt(0)); retires buf reads
  }
#undef STAGE_KV

  // ---- reduce row-sums across the 4 quads, normalize, packed store ----
  lAs += __shfl_xor(lAs, 16, 64); lAs += __shfl_xor(lAs, 32, 64);
  lBs += __shfl_xor(lBs, 16, 64); lBs += __shfl_xor(lBs, 32, 64);
  float invA = 1.f / lAs, invB = 1.f / lBs;
  uint16_t* yb = Y + (size_t)b * NS * ND + (size_t)h * NHS;
  for (int et = 0; et < 4; et++) {
    __align__(8) uint16_t tA[4], tB[4];
    for (int r = 0; r < 4; r++) {
      tA[r] = f2b(oA[et][r] * invA);
      tB[r] = f2b(oB[et][r] * invB);
    }
    *(uint2*)&yb[(size_t)rA * ND + et * 16 + quad * 4] = *(uint2*)tA;
    *(uint2*)&yb[(size_t)rB * ND + et * 16 + quad * 4] = *(uint2*)tB;
  }
}
#else
// ---------------- fallback: round-8 k_attn (LDS-staged K/V + P round-trip) ----------------
__global__ __launch_bounds__(256) void k_attn(
    const uint16_t* __restrict__ Q, const uint16_t* __restrict__ K,
    const uint16_t* __restrict__ VT, uint16_t* __restrict__ Y) {
  __shared__ __align__(16) uint16_t Ks[64][72];
  __shared__ __align__(16) uint16_t Vs[64][72];
  __shared__ __align__(16) uint16_t Ps[4][2][16][72];
  int bh = blockIdx.y;
  int b = bh >> 4, h = bh & 15;
  int ta = blockIdx.x;
  int tb = 31 - ta;
  const uint16_t* Qp = Q + (size_t)bh * (NS * NHS);
  const uint16_t* Kp = K + (size_t)bh * (NS * NHS);
  const uint16_t* Vp = VT + (size_t)bh * (NS * NHS);
  int tid = threadIdx.x;
  int wv = tid >> 6, lane = tid & 63, quad = lane >> 4, l16 = lane & 15;

  int rA = ta * 64 + wv * 16 + l16;
  int rB = tb * 64 + wv * 16 + l16;
  bf16x8 aqA0 = *(const bf16x8*)&Qp[(size_t)rA * NHS + quad * 8];
  bf16x8 aqA1 = *(const bf16x8*)&Qp[(size_t)rA * NHS + 32 + quad * 8];
  bf16x8 aqB0 = *(const bf16x8*)&Qp[(size_t)rB * NHS + quad * 8];
  bf16x8 aqB1 = *(const bf16x8*)&Qp[(size_t)rB * NHS + 32 + quad * 8];

  float lA[4] = {0.f, 0.f, 0.f, 0.f}, lB[4] = {0.f, 0.f, 0.f, 0.f};
  floatx4 oA[4], oB[4];
  for (int ct = 0; ct < 4; ct++) {
    oA[ct] = (floatx4){0.f, 0.f, 0.f, 0.f};
    oB[ct] = (floatx4){0.f, 0.f, 0.f, 0.f};
  }
  for (int kt = 0; kt <= tb; kt++) {
    bool doA = (kt <= ta);
    __syncthreads();
    for (int u = tid; u < 512; u += 256) {
      int row = u >> 3, cg = u & 7;
      *(uint4*)&Ks[row][cg * 8] =
          *(const uint4*)&Kp[(size_t)(kt * 64 + row) * NHS + cg * 8];
    }
    for (int u = tid; u < 512; u += 256) {
      int row = u >> 3, cg = u & 7;
      *(uint4*)&Vs[row][cg * 8] =
          *(const uint4*)&Vp[(size_t)row * NS + kt * 64 + cg * 8];
    }
    __syncthreads();
    floatx4 sA[4], sB[4];
    for (int ct = 0; ct < 4; ct++) {
      bf16x8 kb0 = *(const bf16x8*)&Ks[ct * 16 + l16][quad * 8];
      bf16x8 kb1 = *(const bf16x8*)&Ks[ct * 16 + l16][32 + quad * 8];
      floatx4 c = (floatx4){0.f, 0.f, 0.f, 0.f};
      c = __builtin_amdgcn_mfma_f32_16x16x32_bf16(aqB0, kb0, c, 0, 0, 0);
      c = __builtin_amdgcn_mfma_f32_16x16x32_bf16(aqB1, kb1, c, 0, 0, 0);
      sB[ct] = c;
      if (doA) {
        floatx4 d = (floatx4){0.f, 0.f, 0.f, 0.f};
        d = __builtin_amdgcn_mfma_f32_16x16x32_bf16(aqA0, kb0, d, 0, 0, 0);
        d = __builtin_amdgcn_mfma_f32_16x16x32_bf16(aqA1, kb1, d, 0, 0, 0);
        sA[ct] = d;
      }
    }
    if (kt == tb) {
      int qrb = tb * 64 + wv * 16 + quad * 4;
      for (int ct = 0; ct < 4; ct++) {
        int kg = kt * 64 + ct * 16 + l16;
        for (int r = 0; r < 4; r++)
          sB[ct][r] = (kg <= qrb + r) ? sB[ct][r] : NEG_BIG;
      }
    }
    if (doA && kt == ta) {
      int qrb = ta * 64 + wv * 16 + quad * 4;
      for (int ct = 0; ct < 4; ct++) {
        int kg = kt * 64 + ct * 16 + l16;
        for (int r = 0; r < 4; r++)
          sA[ct][r] = (kg <= qrb + r) ? sA[ct][r] : NEG_BIG;
      }
    }
    for (int ct = 0; ct < 4; ct++)
      for (int r = 0; r < 4; r++) {
        float p = __builtin_amdgcn_exp2f(sB[ct][r]);
        lB[r] += p;
        Ps[wv][1][quad * 4 + r][ct * 16 + l16] = f2b(p);
      }
    if (doA)
      for (int ct = 0; ct < 4; ct++)
        for (int r = 0; r < 4; r++) {
          float p = __builtin_amdgcn_exp2f(sA[ct][r]);
          lA[r] += p;
          Ps[wv][0][quad * 4 + r][ct * 16 + l16] = f2b(p);
        }
    bf16x8 apB0 = *(const bf16x8*)&Ps[wv][1][l16][quad * 8];
    bf16x8 apB1 = *(const bf16x8*)&Ps[wv][1][l16][32 + quad * 8];
    bf16x8 apA0, apA1;
    if (doA) {
      apA0 = *(const bf16x8*)&Ps[wv][0][l16][quad * 8];
      apA1 = *(const bf16x8*)&Ps[wv][0][l16][32 + quad * 8];
    }
    for (int ct = 0; ct < 4; ct++) {
      bf16x8 vb0 = *(const bf16x8*)&Vs[ct * 16 + l16][quad * 8];
      bf16x8 vb1 = *(const bf16x8*)&Vs[ct * 16 + l16][32 + quad * 8];
      oB[ct] = __builtin_amdgcn_mfma_f32_16x16x32_bf16(apB0, vb0, oB[ct], 0, 0, 0);
      oB[ct] = __builtin_amdgcn_mfma_f32_16x16x32_bf16(apB1, vb1, oB[ct], 0, 0, 0);
      if (doA) {
        oA[ct] = __builtin_amdgcn_mfma_f32_16x16x32_bf16(apA0, vb0, oA[ct], 0, 0, 0);
        oA[ct] = __builtin_amdgcn_mfma_f32_16x16x32_bf16(apA1, vb1, oA[ct], 0, 0, 0);
      }
    }
  }
  for (int off = 1; off < 16; off <<= 1)
    for (int r = 0; r < 4; r++) {
      lA[r] += __shfl_xor(lA[r], off, 64);
      lB[r] += __shfl_xor(lB[r], off, 64);
    }
  uint16_t* yb = Y + (size_t)b * NS * ND + (size_t)h * NHS;
  for (int ct = 0; ct < 4; ct++)
    for (int r = 0; r < 4; r++) {
      int sA_ = ta * 64 + wv * 16 + quad * 4 + r;
      int sB_ = tb * 64 + wv * 16 + quad * 4 + r;
      yb[(size_t)sA_ * ND + ct * 16 + l16] = f2b(oA[ct][r] / lA[r]);
      yb[(size_t)sB_ * ND + ct * 16 + l16] = f2b(oB[ct][r] / lB[r]);
    }
}
#endif

// ---------------- kernel 3: output projection + bias, 128x128 2-phase (k_qkv recipe) ----
__global__ __launch_bounds__(512, 4) void k_proj(
    const uint16_t* __restrict__ y, const uint16_t* __restrict__ wot,
    const float* __restrict__ bo, float* __restrict__ out) {
  __shared__ __align__(16) uint16_t L[32768];   // 64 KB

  int bid = blockIdx.x;
  int xcd = bid & 7, idx = bid >> 3;     // 64 tiles per XCD chunk
  int mtile = xcd * 8 + (idx & 7);       // 8 m-tiles per XCD, inner
  int ntile = idx >> 3;                  // 8 n-tiles, outer
  int m0 = mtile * 128;
  int n0 = ntile * 128;

  int tid = threadIdx.x;
  int wave = tid >> 6, lane = tid & 63, quad = lane >> 4, l16 = lane & 15;
  int wr = wave >> 2, wc = wave & 3;

  int swc = ((tid & 3) ^ ((tid >> 4) & 3)) * 8;
  const uint16_t* pA = y + (size_t)(m0 + (tid >> 2)) * ND + swc;
  const uint16_t* pB = wot + (size_t)(n0 + (tid >> 2)) * ND + swc;
  const int stOff = wave * 512;

  const int rq = (quad ^ (l16 >> 2)) * 8;
  const int offA = (wr * 64 + l16) * 32 + rq;
  const int offB = (wc * 32 + l16) * 32 + rq;

  floatx4 acc[4][2];
  #pragma unroll
  for (int i = 0; i < 4; i++)
    #pragma unroll
    for (int j = 0; j < 2; j++) acc[i][j] = (floatx4){0.f, 0.f, 0.f, 0.f};

#define STAGE(A_)                                                               \
  do {                                                                          \
    int a_ = (A_);                                                              \
    if (a_ < 32) {                                                              \
      int ko_ = (a_ >> 1) * 64 + (a_ & 1) * 32;                                 \
      gll16(pA + ko_, &L[(a_ & 3) * 4096 + stOff]);                             \
      gll16(pB + ko_, &L[16384 + (a_ & 3) * 4096 + stOff]);                     \
    }                                                                           \
  } while (0)

#define PH_BAR()                         \
  do {                                   \
    asm volatile("" ::: "memory");       \
    __builtin_amdgcn_s_barrier();        \
    asm volatile("" ::: "memory");       \
  } while (0)

  STAGE(0); STAGE(1); STAGE(2);
  asm volatile("s_waitcnt vmcnt(4)" ::: "memory");
  PH_BAR();

#define MFMA8()                                                                           \
  _Pragma("unroll")                                                                       \
  for (int mt_ = 0; mt_ < 4; mt_++)                                                       \
    _Pragma("unroll")                                                                     \
    for (int nt_ = 0; nt_ < 2; nt_++)                                                     \
      acc[mt_][nt_] = __builtin_amdgcn_mfma_f32_16x16x32_bf16(af[mt_], bfr[nt_], acc[mt_][nt_], 0, 0, 0)

  for (int t = 0; t < 16; ++t) {
    {
      int sA = ((2 * t) & 3) * 4096;
      int sB = 16384 + ((2 * t) & 3) * 4096;
      bf16x8 af[4], bfr[2];
      #pragma unroll
      for (int i = 0; i < 4; i++) af[i] = *(const bf16x8*)&L[sA + offA + i * 512];
      #pragma unroll
      for (int i = 0; i < 2; i++) bfr[i] = *(const bf16x8*)&L[sB + offB + i * 512];
      STAGE(2 * t + 3);
      PH_BAR();
      __builtin_amdgcn_s_setprio(1);
      MFMA8();
      __builtin_amdgcn_s_setprio(0);
      if (t < 15) { asm volatile("s_waitcnt vmcnt(4)" ::: "memory"); }
      else        { asm volatile("s_waitcnt vmcnt(0)" ::: "memory"); }
      PH_BAR();
    }
    {
      int sA = ((2 * t + 1) & 3) * 4096;
      int sB = 16384 + ((2 * t + 1) & 3) * 4096;
      bf16x8 af[4], bfr[2];
      #pragma unroll
      for (int i = 0; i < 4; i++) af[i] = *(const bf16x8*)&L[sA + offA + i * 512];
      #pragma unroll
      for (int i = 0; i < 2; i++) bfr[i] = *(const bf16x8*)&L[sB + offB + i * 512];
      STAGE(2 * t + 4);
      PH_BAR();
      __builtin_amdgcn_s_setprio(1);
      MFMA8();
      __builtin_amdgcn_s_setprio(0);
      if (t < 14)       { asm volatile("s_waitcnt vmcnt(4)" ::: "memory"); }
      else if (t == 14) { asm volatile("s_waitcnt vmcnt(2)" ::: "memory"); }
      if (t < 15) PH_BAR();
    }
  }
#undef MFMA8
#undef STAGE
#undef PH_BAR

  // epilogue: fp32 out + bias (col n = n0 + wc*32 + nt*16 + l16)
  float bv[2];
  #pragma unroll
  for (int nt = 0; nt < 2; nt++) bv[nt] = bo[n0 + wc * 32 + nt * 16 + l16];
  #pragma unroll
  for (int mt = 0; mt < 4; mt++) {
    int s = m0 + wr * 64 + mt * 16 + quad * 4;
    #pragma unroll
    for (int nt = 0; nt < 2; nt++) {
      int n = n0 + wc * 32 + nt * 16 + l16;
      #pragma unroll
      for (int r = 0; r < 4; r++)
        out[(size_t)(s + r) * ND + n] = acc[mt][nt][r] + bv[nt];
    }
  }
}

extern "C" void kernel_launch(void* const* d_in, const int* in_sizes, int n_in,
                              void* d_out, int out_size, void* d_ws, size_t ws_size,
                              hipStream_t stream) {
  const float* x  = (const float*)d_in[0];
  const float* Wq = (const float*)d_in[1];
  const float* Wk = (const float*)d_in[2];
  const float* Wv = (const float*)d_in[3];
  const float* Wo = (const float*)d_in[4];
  const float* bo = (const float*)d_in[5];
  uint16_t* ws = (uint16_t*)d_ws;

  uint16_t* wt = ws;                       // 4 * WSLAB bf16 (Wq_t, Wk_t, Wv_t, Wo_t)
  uint16_t* xb = ws + 4 * WSLAB;           // XSLAB bf16
  uint16_t* q  = xb + XSLAB;               // QSLAB each; k contiguous after q
  uint16_t* k  = q + QSLAB;
  uint16_t* vt = k + QSLAB;                // QSLAB (V transposed, written by k_qkv)
  uint16_t* y  = vt + QSLAB;

  k_prep<<<dim3(5120), dim3(256), 0, stream>>>(x, Wq, Wk, Wv, Wo, xb, wt);
  k_qkv<<<dim3(1536), dim3(512), 0, stream>>>(xb, wt, q, vt);
  k_attn<<<dim3(16, NB * NH), dim3(256), 0, stream>>>(q, k, vt, y);
  k_proj<<<dim3(512), dim3(512), 0, stream>>>(y, wt + 3 * WSLAB, bo, (float*)d_out);
}

// Round 12
// 239.193 us; speedup vs baseline: 1.0624x; 1.0624x over previous
//
#include <hip/hip_runtime.h>
#include <hip/hip_bf16.h>
#include <stdint.h>

#define NB 4
#define NS 2048
#define ND 1024
#define NH 16
#define NHS 64
#define NEG_BIG (-1e30f)
// 1/sqrt(HS) * log2(e): folds softmax exp->exp2 into Q scaling (exactly softmax-invariant)
#define Q_SCALE 0.18033688011112042f

typedef __bf16 bf16x8 __attribute__((ext_vector_type(8)));
typedef float floatx4 __attribute__((ext_vector_type(4)));
typedef short s16x4 __attribute__((ext_vector_type(4)));

#if defined(__has_builtin)
#if __has_builtin(__builtin_amdgcn_mfma_f32_16x16x16bf16_1k)
#define HAVE_MFMA1K 1
#endif
#endif
#ifndef HAVE_MFMA1K
#define HAVE_MFMA1K 0
#endif

static constexpr size_t WSLAB = (size_t)NH * ND * NHS;        // 2^20 elems per weight mat
static constexpr size_t QSLAB = (size_t)NB * NH * NS * NHS;   // 8M elems per QKV/Y slab
static constexpr size_t XSLAB = (size_t)NB * NS * ND;         // 8M elems (x as bf16)

__device__ __forceinline__ uint16_t f2b(float f) {
    union { __hip_bfloat16 h; uint16_t u; } cv;
    cv.h = __float2bfloat16(f);
    return cv.u;
}

// async global->LDS, 16B per lane. LDS dest = wave-uniform base + lane*16 (UNPADDED only).
__device__ __forceinline__ void gll16(const void* g, void* l) {
  __builtin_amdgcn_global_load_lds(
      (__attribute__((address_space(1))) void*)(uintptr_t)g,
      (__attribute__((address_space(3))) void*)(uintptr_t)l,
      16, 0, 0);
}

// ---------------- kernel P: merged x-convert + weight convert/transpose ----------------
__global__ __launch_bounds__(256) void k_prep(
    const float* __restrict__ x, const float* __restrict__ Wq,
    const float* __restrict__ Wk, const float* __restrict__ Wv,
    const float* __restrict__ Wo, uint16_t* __restrict__ xb,
    uint16_t* __restrict__ wt) {
  __shared__ __align__(16) uint16_t T[64][72];
  int bid = blockIdx.x;
  int tid = threadIdx.x;
  if (bid < 4096) {
    size_t i0 = ((size_t)bid * 256 + tid) * 8;
    float4 f0 = *(const float4*)&x[i0];
    float4 f1 = *(const float4*)&x[i0 + 4];
    __align__(16) uint16_t tmp[8];
    tmp[0] = f2b(f0.x); tmp[1] = f2b(f0.y); tmp[2] = f2b(f0.z); tmp[3] = f2b(f0.w);
    tmp[4] = f2b(f1.x); tmp[5] = f2b(f1.y); tmp[6] = f2b(f1.z); tmp[7] = f2b(f1.w);
    *(uint4*)&xb[i0] = *(uint4*)tmp;
    return;
  }
  bid -= 4096;
  const float* src; uint16_t* dst;
  int srcStride, dstStride, r0, c0;
  if (bid < 768) {
    int mat = bid >> 8;
    int rem = bid & 255;
    int h = rem >> 4, dt = rem & 15;
    const float* W = (mat == 0) ? Wq : (mat == 1) ? Wk : Wv;
    src = W + (size_t)h * (ND * NHS);
    dst = wt + (size_t)mat * WSLAB + (size_t)h * (NHS * ND);
    srcStride = NHS; dstStride = ND;
    r0 = dt * 64; c0 = 0;
  } else {
    int rem = bid - 768;
    int dt = rem >> 4, et = rem & 15;
    src = Wo; dst = wt + 3 * WSLAB;
    srcStride = ND; dstStride = ND;
    r0 = dt * 64; c0 = et * 64;
  }
  for (int u = tid; u < 1024; u += 256) {
    int row = u >> 4, cq = u & 15;
    float4 f = *(const float4*)&src[(size_t)(r0 + row) * srcStride + c0 + cq * 4];
    uint16_t* p = &T[row][cq * 4];
    p[0] = f2b(f.x); p[1] = f2b(f.y); p[2] = f2b(f.z); p[3] = f2b(f.w);
  }
  __syncthreads();
  for (int u = tid; u < 512; u += 256) {
    int c = u >> 3, cg = u & 7;
    __align__(16) uint16_t tmp[8];
    for (int j = 0; j < 8; j++) tmp[j] = T[cg * 8 + j][c];
    *(uint4*)&dst[(size_t)(c0 + c) * dstStride + r0 + cg * 8] = *(uint4*)tmp;
  }
}

// ---------------- kernel 1: fused QKV GEMM, 128x128 2-phase, 2 blocks/CU + T2 swizzle ----
// LOCKED (round 10): five structures measured 70.7-77.3us (~700-730 TF, 28-31% MfmaUtil):
// 256²-8slot (77.3), 256²-4slot (74.0), 128x256-packed (73.8), THIS (70.7, best),
// 256x128-counted-vmcnt/144KB (71.5, 1 blk/CU). The 2-phase stage+vmcnt+barrier critical
// path is the plateau; partial T3/T4 embodiments revert to it, and the full 8-phase
// co-design hit L2-thrash (r1) / occupancy (r10) walls on this K=1024 3-matrix shape.
// Do not re-trade without a fundamentally different schedule.
__global__ __launch_bounds__(512, 4) void k_qkv(
    const uint16_t* __restrict__ xb, const uint16_t* __restrict__ wt,
    uint16_t* __restrict__ qk, uint16_t* __restrict__ vt) {
  __shared__ __align__(16) uint16_t L[32768];   // 64 KB

  int bid = blockIdx.x;
  int xcd = bid & 7, idx = bid >> 3;     // 192 tiles per XCD chunk
  int mtile = xcd * 8 + (idx & 7);       // 8 m-tiles per XCD, inner (2MB A L2-resident)
  int ntile = idx >> 3;                  // 24 n-tiles, outer
  int m0 = mtile * 128;
  int n0 = ntile * 128;

  int tid = threadIdx.x;
  int wave = tid >> 6, lane = tid & 63, quad = lane >> 4, l16 = lane & 15;
  int wr = wave >> 2, wc = wave & 3;

  // staging: thread covers (row = tid>>2, chunk = tid&3) of a 128x32 half.
  // T2 pre-swizzle of the GLOBAL source chunk: key = (row>>2)&3 = (tid>>4)&3.
  int swc = ((tid & 3) ^ ((tid >> 4) & 3)) * 8;
  const uint16_t* pA = xb + (size_t)(m0 + (tid >> 2)) * ND + swc;
  const uint16_t* pB = wt + (size_t)(n0 + (tid >> 2)) * ND + swc;
  const int stOff = wave * 512;          // wave-uniform LDS stage base (u16)

  // frag-read bases (u16 within a slot); chunk XOR'd with the same key
  const int rq = (quad ^ (l16 >> 2)) * 8;
  const int offA = (wr * 64 + l16) * 32 + rq;
  const int offB = (wc * 32 + l16) * 32 + rq;

  floatx4 acc[4][2];
  #pragma unroll
  for (int i = 0; i < 4; i++)
    #pragma unroll
    for (int j = 0; j < 2; j++) acc[i][j] = (floatx4){0.f, 0.f, 0.f, 0.f};

#define STAGE(A_)                                                               \
  do {                                                                          \
    int a_ = (A_);                                                              \
    if (a_ < 32) {                                                              \
      int ko_ = (a_ >> 1) * 64 + (a_ & 1) * 32;                                 \
      gll16(pA + ko_, &L[(a_ & 3) * 4096 + stOff]);                             \
      gll16(pB + ko_, &L[16384 + (a_ & 3) * 4096 + stOff]);                     \
    }                                                                           \
  } while (0)

#define PH_BAR()                         \
  do {                                   \
    asm volatile("" ::: "memory");       \
    __builtin_amdgcn_s_barrier();        \
    asm volatile("" ::: "memory");       \
  } while (0)

  // prologue: lo(0), hi(0), lo(1); drain until lo(0) landed (4 newer loads in flight)
  STAGE(0); STAGE(1); STAGE(2);
  asm volatile("s_waitcnt vmcnt(4)" ::: "memory");
  PH_BAR();

#define MFMA8()                                                                           \
  _Pragma("unroll")                                                                       \
  for (int mt_ = 0; mt_ < 4; mt_++)                                                       \
    _Pragma("unroll")                                                                     \
    for (int nt_ = 0; nt_ < 2; nt_++)                                                     \
      acc[mt_][nt_] = __builtin_amdgcn_mfma_f32_16x16x32_bf16(af[mt_], bfr[nt_], acc[mt_][nt_], 0, 0, 0)

  for (int t = 0; t < 16; ++t) {
    {
      // ---- ph0: read lo(t) [slot (2t)&3], stage hi(t+1) ----
      int sA = ((2 * t) & 3) * 4096;
      int sB = 16384 + ((2 * t) & 3) * 4096;
      bf16x8 af[4], bfr[2];
      #pragma unroll
      for (int i = 0; i < 4; i++) af[i] = *(const bf16x8*)&L[sA + offA + i * 512];
      #pragma unroll
      for (int i = 0; i < 2; i++) bfr[i] = *(const bf16x8*)&L[sB + offB + i * 512];
      STAGE(2 * t + 3);
      PH_BAR();
      __builtin_amdgcn_s_setprio(1);
      MFMA8();
      __builtin_amdgcn_s_setprio(0);
      if (t < 15) { asm volatile("s_waitcnt vmcnt(4)" ::: "memory"); }
      else        { asm volatile("s_waitcnt vmcnt(0)" ::: "memory"); }
      PH_BAR();
    }
    {
      // ---- ph1: read hi(t) [slot (2t+1)&3], stage lo(t+2) ----
      int sA = ((2 * t + 1) & 3) * 4096;
      int sB = 16384 + ((2 * t + 1) & 3) * 4096;
      bf16x8 af[4], bfr[2];
      #pragma unroll
      for (int i = 0; i < 4; i++) af[i] = *(const bf16x8*)&L[sA + offA + i * 512];
      #pragma unroll
      for (int i = 0; i < 2; i++) bfr[i] = *(const bf16x8*)&L[sB + offB + i * 512];
      STAGE(2 * t + 4);
      PH_BAR();
      __builtin_amdgcn_s_setprio(1);
      MFMA8();
      __builtin_amdgcn_s_setprio(0);
      if (t < 14)       { asm volatile("s_waitcnt vmcnt(4)" ::: "memory"); }
      else if (t == 14) { asm volatile("s_waitcnt vmcnt(2)" ::: "memory"); }
      if (t < 15) PH_BAR();
    }
  }
#undef MFMA8
#undef STAGE
#undef PH_BAR

  // n-decomposition: head hh, element e within head
  int matid = n0 >> 10;
  int b = m0 >> 11;
  if (matid == 2) {
    // ---- V blocks: store V^T ([b,h,e,s]) directly from registers (uint2, s-contiguous) ----
    int hh = ((n0 - 2048) >> 6) + (wc >> 1);
    #pragma unroll
    for (int nt = 0; nt < 2; nt++) {
      int e = (wc & 1) * 32 + nt * 16 + l16;
      uint16_t* vrow = vt + ((size_t)(b * 16 + hh) * 64 + e) * NS;
      #pragma unroll
      for (int mt = 0; mt < 4; mt++) {
        __align__(8) uint16_t t4v[4];
        #pragma unroll
        for (int r = 0; r < 4; r++) t4v[r] = f2b(acc[mt][nt][r]);
        int s = (m0 & 2047) + wr * 64 + mt * 16 + quad * 4;
        *(uint2*)&vrow[s] = *(uint2*)t4v;
      }
    }
  } else {
    // ---- Q/K blocks: scatter to [b,h,s,e] with Q pre-scale ----
    float scale = (matid == 0) ? Q_SCALE : 1.0f;
    uint16_t* base = qk + (size_t)matid * QSLAB;
    int hh = ((n0 & 1023) >> 6) + (wc >> 1);
    #pragma unroll
    for (int mt = 0; mt < 4; mt++) {
      int s = (m0 & 2047) + wr * 64 + mt * 16 + quad * 4;
      size_t rbase = ((size_t)(b * 16 + hh) * NS + s) * NHS;
      #pragma unroll
      for (int nt = 0; nt < 2; nt++)
        #pragma unroll
        for (int r = 0; r < 4; r++)
          base[rbase + (size_t)r * NHS + (wc & 1) * 32 + nt * 16 + l16] =
              f2b(acc[mt][nt][r] * scale);
    }
  }
}

#if HAVE_MFMA1K
// ---------------- kernel 2: causal attention, S^T trick, gll16 staging, 1 barrier/step --
// Round-11 change (index permutation ONLY, body byte-identical): 1D grid of 1024 with
// bh = bid&63, w = bid>>6, ta = (w&8) ? 15-(w&7) : w.
// Why: block work = 32-ta steps (17..32, 1.9x spread). Old (16,64) grid put the SAME ta
// on all 4 co-resident blocks of a CU (bids c,c+256,c+512,c+768 share x = c&15) ->
// critical-path CUs did 128 steps vs 98 mean (~23% tail idle; OccupancyPercent ~30%).
// New map: each CU's four blocks have raws {r, r+4, 15-r, 11-r} -> steps sum exactly 98
// for every r (perfect balance under the spread dispatch model). Bonus: bh%8 = bid%8 ->
// all 16 sharers of a bh's K/V on ONE XCD (r6's verified FETCH reduction, without the
// r6 restructure that caused its regression).
__global__ __launch_bounds__(256, 4) void k_attn(
    const uint16_t* __restrict__ Q, const uint16_t* __restrict__ K,
    const uint16_t* __restrict__ VT, uint16_t* __restrict__ Y) {
  __shared__ __align__(16) uint16_t Ks[2][4096];   // [buf][k*64 + swz e-chunk]
  __shared__ __align__(16) uint16_t Vs[2][4096];   // [buf][e*64 + swz key-chunk]
  int bid = blockIdx.x;
  int bh = bid & 63;
  int w = bid >> 6;
  int ta = (w & 8) ? (15 - (w & 7)) : w;   // 0..15, CU-balanced + XCD-local (see header)
  int b = bh >> 4, h = bh & 15;
  int tb = 31 - ta;          // 16..31
  const uint16_t* Qp = Q + (size_t)bh * (NS * NHS);
  const uint16_t* Kp = K + (size_t)bh * (NS * NHS);
  const uint16_t* Vp = VT + (size_t)bh * (NS * NHS);  // [e][key]
  int tid = threadIdx.x;
  int wv = tid >> 6, lane = tid & 63, quad = lane >> 4, l16 = lane & 15;

  // gll16 staging map: wave wv covers rows [wv*16, wv*16+16) in two 8-row groups.
  int srow = lane >> 3;                       // row offset in 8-row group (= row&7)
  int swOff = ((lane & 7) ^ srow) * 8;        // pre-swizzled source chunk (u16)
  int stRow0 = wv * 16 + srow;
  int stRow1 = wv * 16 + 8 + srow;
  const int dst0 = wv * 1024;                 // wave-uniform LDS dest (u16)
  const int dst1 = wv * 1024 + 512;

#define STAGE_KV(KT, BUF)                                                         \
  do {                                                                            \
    int kt_ = (KT);                                                               \
    gll16(Kp + (size_t)(kt_ * 64 + stRow0) * NHS + swOff, &Ks[BUF][dst0]);        \
    gll16(Kp + (size_t)(kt_ * 64 + stRow1) * NHS + swOff, &Ks[BUF][dst1]);        \
    gll16(Vp + (size_t)stRow0 * NS + kt_ * 64 + swOff, &Vs[BUF][dst0]);           \
    gll16(Vp + (size_t)stRow1 * NS + kt_ * 64 + swOff, &Vs[BUF][dst1]);           \
  } while (0)

  // swizzled frag-read column offsets (u16 within a 64-u16 row)
  int e3 = l16 & 7;
  int kc0 = (quad ^ e3) * 8;              // kb0: logical chunk quad
  int kc1 = ((4 | quad) ^ e3) * 8;        // kb1: logical chunk 4+quad
  int vql = (quad & 1) * 4;
  int vqh = quad >> 1;
  int vcol[4];
  #pragma unroll
  for (int ct = 0; ct < 4; ct++)
    vcol[ct] = (((ct * 2 + vqh) ^ e3) * 8) + vql;

  // Q fragments from global; B operand of S^T = K.Q^T (n = q-row = l16)
  int rA = ta * 64 + wv * 16 + l16;
  int rB = tb * 64 + wv * 16 + l16;
  bf16x8 aqA0 = *(const bf16x8*)&Qp[(size_t)rA * NHS + quad * 8];
  bf16x8 aqA1 = *(const bf16x8*)&Qp[(size_t)rA * NHS + 32 + quad * 8];
  bf16x8 aqB0 = *(const bf16x8*)&Qp[(size_t)rB * NHS + quad * 8];
  bf16x8 aqB1 = *(const bf16x8*)&Qp[(size_t)rB * NHS + 32 + quad * 8];

  float lAs = 0.f, lBs = 0.f;          // per-lane row-sum (all p of a lane share q-row l16)
  floatx4 oA[4], oB[4];                // O^T accumulators, one per e-tile
  for (int et = 0; et < 4; et++) {
    oA[et] = (floatx4){0.f, 0.f, 0.f, 0.f};
    oB[et] = (floatx4){0.f, 0.f, 0.f, 0.f};
  }

  // prologue: tile 0 -> buf0; __syncthreads' intrinsic vmcnt(0) waits it (and Q loads)
  STAGE_KV(0, 0);
  __syncthreads();

  for (int kt = 0; kt <= tb; kt++) {
    int cur = kt & 1;
    if (kt < tb) STAGE_KV(kt + 1, cur ^ 1);   // buf^1 free since end-of-step kt-1
    const uint16_t* KB = &Ks[cur][0];
    const uint16_t* VB = &Vs[cur][0];
    bool doA = (kt <= ta);  // uniform across block

    // ---- S^T tiles + mask + exp2 + pack (P^T lands in B-layout of K=16 MFMA) ----
    s16x4 pbA[4], pbB[4];
    #pragma unroll
    for (int ct = 0; ct < 4; ct++) {
      int krow = (ct * 16 + l16) * 64;
      bf16x8 kb0 = *(const bf16x8*)&KB[krow + kc0];
      bf16x8 kb1 = *(const bf16x8*)&KB[krow + kc1];
      int key = kt * 64 + ct * 16 + quad * 4;
      floatx4 c = (floatx4){0.f, 0.f, 0.f, 0.f};
      c = __builtin_amdgcn_mfma_f32_16x16x32_bf16(kb0, aqB0, c, 0, 0, 0);
      c = __builtin_amdgcn_mfma_f32_16x16x32_bf16(kb1, aqB1, c, 0, 0, 0);
      #pragma unroll
      for (int r = 0; r < 4; r++) {
        float s = (kt == tb && key + r > rB) ? NEG_BIG : c[r];
        float p = __builtin_amdgcn_exp2f(s);
        lBs += p;
        pbB[ct][r] = (short)f2b(p);
      }
      if (doA) {
        floatx4 d = (floatx4){0.f, 0.f, 0.f, 0.f};
        d = __builtin_amdgcn_mfma_f32_16x16x32_bf16(kb0, aqA0, d, 0, 0, 0);
        d = __builtin_amdgcn_mfma_f32_16x16x32_bf16(kb1, aqA1, d, 0, 0, 0);
        #pragma unroll
        for (int r = 0; r < 4; r++) {
          float s = (kt == ta && key + r > rA) ? NEG_BIG : d[r];
          float p = __builtin_amdgcn_exp2f(s);
          lAs += p;
          pbA[ct][r] = (short)f2b(p);
        }
      }
    }
    // ---- O^T += V^T . P^T (A-frag = 4 keys of V^T via swizzled 8B reads) ----
    #pragma unroll
    for (int et = 0; et < 4; et++) {
      int vrow = (et * 16 + l16) * 64;
      #pragma unroll
      for (int ct = 0; ct < 4; ct++) {
        s16x4 va = *(const s16x4*)&VB[vrow + vcol[ct]];
        oB[et] = __builtin_amdgcn_mfma_f32_16x16x16bf16_1k(va, pbB[ct], oB[et], 0, 0, 0);
        if (doA)
          oA[et] = __builtin_amdgcn_mfma_f32_16x16x16bf16_1k(va, pbA[ct], oA[et], 0, 0, 0);
      }
    }
    __syncthreads();   // publishes buf^1 gll16s (intrinsic vmcnt(0)); retires buf reads
  }
#undef STAGE_KV

  // ---- reduce row-sums across the 4 quads, normalize, packed store ----
  lAs += __shfl_xor(lAs, 16, 64); lAs += __shfl_xor(lAs, 32, 64);
  lBs += __shfl_xor(lBs, 16, 64); lBs += __shfl_xor(lBs, 32, 64);
  float invA = 1.f / lAs, invB = 1.f / lBs;
  uint16_t* yb = Y + (size_t)b * NS * ND + (size_t)h * NHS;
  for (int et = 0; et < 4; et++) {
    __align__(8) uint16_t tA[4], tB[4];
    for (int r = 0; r < 4; r++) {
      tA[r] = f2b(oA[et][r] * invA);
      tB[r] = f2b(oB[et][r] * invB);
    }
    *(uint2*)&yb[(size_t)rA * ND + et * 16 + quad * 4] = *(uint2*)tA;
    *(uint2*)&yb[(size_t)rB * ND + et * 16 + quad * 4] = *(uint2*)tB;
  }
}
#else
// ---------------- fallback: round-8 k_attn (LDS-staged K/V + P round-trip) ----------------
__global__ __launch_bounds__(256) void k_attn(
    const uint16_t* __restrict__ Q, const uint16_t* __restrict__ K,
    const uint16_t* __restrict__ VT, uint16_t* __restrict__ Y) {
  __shared__ __align__(16) uint16_t Ks[64][72];
  __shared__ __align__(16) uint16_t Vs[64][72];
  __shared__ __align__(16) uint16_t Ps[4][2][16][72];
  int bid = blockIdx.x;
  int bh = bid & 63;
  int w = bid >> 6;
  int ta = (w & 8) ? (15 - (w & 7)) : w;
  int b = bh >> 4, h = bh & 15;
  int tb = 31 - ta;
  const uint16_t* Qp = Q + (size_t)bh * (NS * NHS);
  const uint16_t* Kp = K + (size_t)bh * (NS * NHS);
  const uint16_t* Vp = VT + (size_t)bh * (NS * NHS);
  int tid = threadIdx.x;
  int wv = tid >> 6, lane = tid & 63, quad = lane >> 4, l16 = lane & 15;

  int rA = ta * 64 + wv * 16 + l16;
  int rB = tb * 64 + wv * 16 + l16;
  bf16x8 aqA0 = *(const bf16x8*)&Qp[(size_t)rA * NHS + quad * 8];
  bf16x8 aqA1 = *(const bf16x8*)&Qp[(size_t)rA * NHS + 32 + quad * 8];
  bf16x8 aqB0 = *(const bf16x8*)&Qp[(size_t)rB * NHS + quad * 8];
  bf16x8 aqB1 = *(const bf16x8*)&Qp[(size_t)rB * NHS + 32 + quad * 8];

  float lA[4] = {0.f, 0.f, 0.f, 0.f}, lB[4] = {0.f, 0.f, 0.f, 0.f};
  floatx4 oA[4], oB[4];
  for (int ct = 0; ct < 4; ct++) {
    oA[ct] = (floatx4){0.f, 0.f, 0.f, 0.f};
    oB[ct] = (floatx4){0.f, 0.f, 0.f, 0.f};
  }
  for (int kt = 0; kt <= tb; kt++) {
    bool doA = (kt <= ta);
    __syncthreads();
    for (int u = tid; u < 512; u += 256) {
      int row = u >> 3, cg = u & 7;
      *(uint4*)&Ks[row][cg * 8] =
          *(const uint4*)&Kp[(size_t)(kt * 64 + row) * NHS + cg * 8];
    }
    for (int u = tid; u < 512; u += 256) {
      int row = u >> 3, cg = u & 7;
      *(uint4*)&Vs[row][cg * 8] =
          *(const uint4*)&Vp[(size_t)row * NS + kt * 64 + cg * 8];
    }
    __syncthreads();
    floatx4 sA[4], sB[4];
    for (int ct = 0; ct < 4; ct++) {
      bf16x8 kb0 = *(const bf16x8*)&Ks[ct * 16 + l16][quad * 8];
      bf16x8 kb1 = *(const bf16x8*)&Ks[ct * 16 + l16][32 + quad * 8];
      floatx4 c = (floatx4){0.f, 0.f, 0.f, 0.f};
      c = __builtin_amdgcn_mfma_f32_16x16x32_bf16(aqB0, kb0, c, 0, 0, 0);
      c = __builtin_amdgcn_mfma_f32_16x16x32_bf16(aqB1, kb1, c, 0, 0, 0);
      sB[ct] = c;
      if (doA) {
        floatx4 d = (floatx4){0.f, 0.f, 0.f, 0.f};
        d = __builtin_amdgcn_mfma_f32_16x16x32_bf16(aqA0, kb0, d, 0, 0, 0);
        d = __builtin_amdgcn_mfma_f32_16x16x32_bf16(aqA1, kb1, d, 0, 0, 0);
        sA[ct] = d;
      }
    }
    if (kt == tb) {
      int qrb = tb * 64 + wv * 16 + quad * 4;
      for (int ct = 0; ct < 4; ct++) {
        int kg = kt * 64 + ct * 16 + l16;
        for (int r = 0; r < 4; r++)
          sB[ct][r] = (kg <= qrb + r) ? sB[ct][r] : NEG_BIG;
      }
    }
    if (doA && kt == ta) {
      int qrb = ta * 64 + wv * 16 + quad * 4;
      for (int ct = 0; ct < 4; ct++) {
        int kg = kt * 64 + ct * 16 + l16;
        for (int r = 0; r < 4; r++)
          sA[ct][r] = (kg <= qrb + r) ? sA[ct][r] : NEG_BIG;
      }
    }
    for (int ct = 0; ct < 4; ct++)
      for (int r = 0; r < 4; r++) {
        float p = __builtin_amdgcn_exp2f(sB[ct][r]);
        lB[r] += p;
        Ps[wv][1][quad * 4 + r][ct * 16 + l16] = f2b(p);
      }
    if (doA)
      for (int ct = 0; ct < 4; ct++)
        for (int r = 0; r < 4; r++) {
          float p = __builtin_amdgcn_exp2f(sA[ct][r]);
          lA[r] += p;
          Ps[wv][0][quad * 4 + r][ct * 16 + l16] = f2b(p);
        }
    bf16x8 apB0 = *(const bf16x8*)&Ps[wv][1][l16][quad * 8];
    bf16x8 apB1 = *(const bf16x8*)&Ps[wv][1][l16][32 + quad * 8];
    bf16x8 apA0, apA1;
    if (doA) {
      apA0 = *(const bf16x8*)&Ps[wv][0][l16][quad * 8];
      apA1 = *(const bf16x8*)&Ps[wv][0][l16][32 + quad * 8];
    }
    for (int ct = 0; ct < 4; ct++) {
      bf16x8 vb0 = *(const bf16x8*)&Vs[ct * 16 + l16][quad * 8];
      bf16x8 vb1 = *(const bf16x8*)&Vs[ct * 16 + l16][32 + quad * 8];
      oB[ct] = __builtin_amdgcn_mfma_f32_16x16x32_bf16(apB0, vb0, oB[ct], 0, 0, 0);
      oB[ct] = __builtin_amdgcn_mfma_f32_16x16x32_bf16(apB1, vb1, oB[ct], 0, 0, 0);
      if (doA) {
        oA[ct] = __builtin_amdgcn_mfma_f32_16x16x32_bf16(apA0, vb0, oA[ct], 0, 0, 0);
        oA[ct] = __builtin_amdgcn_mfma_f32_16x16x32_bf16(apA1, vb1, oA[ct], 0, 0, 0);
      }
    }
  }
  for (int off = 1; off < 16; off <<= 1)
    for (int r = 0; r < 4; r++) {
      lA[r] += __shfl_xor(lA[r], off, 64);
      lB[r] += __shfl_xor(lB[r], off, 64);
    }
  uint16_t* yb = Y + (size_t)b * NS * ND + (size_t)h * NHS;
  for (int ct = 0; ct < 4; ct++)
    for (int r = 0; r < 4; r++) {
      int sA_ = ta * 64 + wv * 16 + quad * 4 + r;
      int sB_ = tb * 64 + wv * 16 + quad * 4 + r;
      yb[(size_t)sA_ * ND + ct * 16 + l16] = f2b(oA[ct][r] / lA[r]);
      yb[(size_t)sB_ * ND + ct * 16 + l16] = f2b(oB[ct][r] / lB[r]);
    }
}
#endif

// ---------------- kernel 3: output projection + bias, 128x128 2-phase (k_qkv recipe) ----
__global__ __launch_bounds__(512, 4) void k_proj(
    const uint16_t* __restrict__ y, const uint16_t* __restrict__ wot,
    const float* __restrict__ bo, float* __restrict__ out) {
  __shared__ __align__(16) uint16_t L[32768];   // 64 KB

  int bid = blockIdx.x;
  int xcd = bid & 7, idx = bid >> 3;     // 64 tiles per XCD chunk
  int mtile = xcd * 8 + (idx & 7);       // 8 m-tiles per XCD, inner
  int ntile = idx >> 3;                  // 8 n-tiles, outer
  int m0 = mtile * 128;
  int n0 = ntile * 128;

  int tid = threadIdx.x;
  int wave = tid >> 6, lane = tid & 63, quad = lane >> 4, l16 = lane & 15;
  int wr = wave >> 2, wc = wave & 3;

  int swc = ((tid & 3) ^ ((tid >> 4) & 3)) * 8;
  const uint16_t* pA = y + (size_t)(m0 + (tid >> 2)) * ND + swc;
  const uint16_t* pB = wot + (size_t)(n0 + (tid >> 2)) * ND + swc;
  const int stOff = wave * 512;

  const int rq = (quad ^ (l16 >> 2)) * 8;
  const int offA = (wr * 64 + l16) * 32 + rq;
  const int offB = (wc * 32 + l16) * 32 + rq;

  floatx4 acc[4][2];
  #pragma unroll
  for (int i = 0; i < 4; i++)
    #pragma unroll
    for (int j = 0; j < 2; j++) acc[i][j] = (floatx4){0.f, 0.f, 0.f, 0.f};

#define STAGE(A_)                                                               \
  do {                                                                          \
    int a_ = (A_);                                                              \
    if (a_ < 32) {                                                              \
      int ko_ = (a_ >> 1) * 64 + (a_ & 1) * 32;                                 \
      gll16(pA + ko_, &L[(a_ & 3) * 4096 + stOff]);                             \
      gll16(pB + ko_, &L[16384 + (a_ & 3) * 4096 + stOff]);                     \
    }                                                                           \
  } while (0)

#define PH_BAR()                         \
  do {                                   \
    asm volatile("" ::: "memory");       \
    __builtin_amdgcn_s_barrier();        \
    asm volatile("" ::: "memory");       \
  } while (0)

  STAGE(0); STAGE(1); STAGE(2);
  asm volatile("s_waitcnt vmcnt(4)" ::: "memory");
  PH_BAR();

#define MFMA8()                                                                           \
  _Pragma("unroll")                                                                       \
  for (int mt_ = 0; mt_ < 4; mt_++)                                                       \
    _Pragma("unroll")                                                                     \
    for (int nt_ = 0; nt_ < 2; nt_++)                                                     \
      acc[mt_][nt_] = __builtin_amdgcn_mfma_f32_16x16x32_bf16(af[mt_], bfr[nt_], acc[mt_][nt_], 0, 0, 0)

  for (int t = 0; t < 16; ++t) {
    {
      int sA = ((2 * t) & 3) * 4096;
      int sB = 16384 + ((2 * t) & 3) * 4096;
      bf16x8 af[4], bfr[2];
      #pragma unroll
      for (int i = 0; i < 4; i++) af[i] = *(const bf16x8*)&L[sA + offA + i * 512];
      #pragma unroll
      for (int i = 0; i < 2; i++) bfr[i] = *(const bf16x8*)&L[sB + offB + i * 512];
      STAGE(2 * t + 3);
      PH_BAR();
      __builtin_amdgcn_s_setprio(1);
      MFMA8();
      __builtin_amdgcn_s_setprio(0);
      if (t < 15) { asm volatile("s_waitcnt vmcnt(4)" ::: "memory"); }
      else        { asm volatile("s_waitcnt vmcnt(0)" ::: "memory"); }
      PH_BAR();
    }
    {
      int sA = ((2 * t + 1) & 3) * 4096;
      int sB = 16384 + ((2 * t + 1) & 3) * 4096;
      bf16x8 af[4], bfr[2];
      #pragma unroll
      for (int i = 0; i < 4; i++) af[i] = *(const bf16x8*)&L[sA + offA + i * 512];
      #pragma unroll
      for (int i = 0; i < 2; i++) bfr[i] = *(const bf16x8*)&L[sB + offB + i * 512];
      STAGE(2 * t + 4);
      PH_BAR();
      __builtin_amdgcn_s_setprio(1);
      MFMA8();
      __builtin_amdgcn_s_setprio(0);
      if (t < 14)       { asm volatile("s_waitcnt vmcnt(4)" ::: "memory"); }
      else if (t == 14) { asm volatile("s_waitcnt vmcnt(2)" ::: "memory"); }
      if (t < 15) PH_BAR();
    }
  }
#undef MFMA8
#undef STAGE
#undef PH_BAR

  // epilogue: fp32 out + bias (col n = n0 + wc*32 + nt*16 + l16)
  float bv[2];
  #pragma unroll
  for (int nt = 0; nt < 2; nt++) bv[nt] = bo[n0 + wc * 32 + nt * 16 + l16];
  #pragma unroll
  for (int mt = 0; mt < 4; mt++) {
    int s = m0 + wr * 64 + mt * 16 + quad * 4;
    #pragma unroll
    for (int nt = 0; nt < 2; nt++) {
      int n = n0 + wc * 32 + nt * 16 + l16;
      #pragma unroll
      for (int r = 0; r < 4; r++)
        out[(size_t)(s + r) * ND + n] = acc[mt][nt][r] + bv[nt];
    }
  }
}

extern "C" void kernel_launch(void* const* d_in, const int* in_sizes, int n_in,
                              void* d_out, int out_size, void* d_ws, size_t ws_size,
                              hipStream_t stream) {
  const float* x  = (const float*)d_in[0];
  const float* Wq = (const float*)d_in[1];
  const float* Wk = (const float*)d_in[2];
  const float* Wv = (const float*)d_in[3];
  const float* Wo = (const float*)d_in[4];
  const float* bo = (const float*)d_in[5];
  uint16_t* ws = (uint16_t*)d_ws;

  uint16_t* wt = ws;                       // 4 * WSLAB bf16 (Wq_t, Wk_t, Wv_t, Wo_t)
  uint16_t* xb = ws + 4 * WSLAB;           // XSLAB bf16
  uint16_t* q  = xb + XSLAB;               // QSLAB each; k contiguous after q
  uint16_t* k  = q + QSLAB;
  uint16_t* vt = k + QSLAB;                // QSLAB (V transposed, written by k_qkv)
  uint16_t* y  = vt + QSLAB;

  k_prep<<<dim3(5120), dim3(256), 0, stream>>>(x, Wq, Wk, Wv, Wo, xb, wt);
  k_qkv<<<dim3(1536), dim3(512), 0, stream>>>(xb, wt, q, vt);
  k_attn<<<dim3(1024), dim3(256), 0, stream>>>(q, k, vt, y);
  k_proj<<<dim3(512), dim3(512), 0, stream>>>(y, wt + 3 * WSLAB, bo, (float*)d_out);
}

// Round 13
// 228.848 us; speedup vs baseline: 1.1104x; 1.0452x over previous
//
#include <hip/hip_runtime.h>
#include <hip/hip_bf16.h>
#include <stdint.h>

#define NB 4
#define NS 2048
#define ND 1024
#define NH 16
#define NHS 64
#define NEG_BIG (-1e30f)
// 1/sqrt(HS) * log2(e): folds softmax exp->exp2 into Q scaling (exactly softmax-invariant)
#define Q_SCALE 0.18033688011112042f

typedef __bf16 bf16x8 __attribute__((ext_vector_type(8)));
typedef float floatx4 __attribute__((ext_vector_type(4)));
typedef short s16x4 __attribute__((ext_vector_type(4)));

#if defined(__has_builtin)
#if __has_builtin(__builtin_amdgcn_mfma_f32_16x16x16bf16_1k)
#define HAVE_MFMA1K 1
#endif
#endif
#ifndef HAVE_MFMA1K
#define HAVE_MFMA1K 0
#endif

static constexpr size_t WSLAB = (size_t)NH * ND * NHS;        // 2^20 elems per weight mat
static constexpr size_t QSLAB = (size_t)NB * NH * NS * NHS;   // 8M elems per QKV/Y slab
static constexpr size_t XSLAB = (size_t)NB * NS * ND;         // 8M elems (x as bf16)

__device__ __forceinline__ uint16_t f2b(float f) {
    union { __hip_bfloat16 h; uint16_t u; } cv;
    cv.h = __float2bfloat16(f);
    return cv.u;
}

// async global->LDS, 16B per lane. LDS dest = wave-uniform base + lane*16 (UNPADDED only).
__device__ __forceinline__ void gll16(const void* g, void* l) {
  __builtin_amdgcn_global_load_lds(
      (__attribute__((address_space(1))) void*)(uintptr_t)g,
      (__attribute__((address_space(3))) void*)(uintptr_t)l,
      16, 0, 0);
}

// ---------------- kernel P: merged x-convert + weight convert/transpose ----------------
__global__ __launch_bounds__(256) void k_prep(
    const float* __restrict__ x, const float* __restrict__ Wq,
    const float* __restrict__ Wk, const float* __restrict__ Wv,
    const float* __restrict__ Wo, uint16_t* __restrict__ xb,
    uint16_t* __restrict__ wt) {
  __shared__ __align__(16) uint16_t T[64][72];
  int bid = blockIdx.x;
  int tid = threadIdx.x;
  if (bid < 4096) {
    size_t i0 = ((size_t)bid * 256 + tid) * 8;
    float4 f0 = *(const float4*)&x[i0];
    float4 f1 = *(const float4*)&x[i0 + 4];
    __align__(16) uint16_t tmp[8];
    tmp[0] = f2b(f0.x); tmp[1] = f2b(f0.y); tmp[2] = f2b(f0.z); tmp[3] = f2b(f0.w);
    tmp[4] = f2b(f1.x); tmp[5] = f2b(f1.y); tmp[6] = f2b(f1.z); tmp[7] = f2b(f1.w);
    *(uint4*)&xb[i0] = *(uint4*)tmp;
    return;
  }
  bid -= 4096;
  const float* src; uint16_t* dst;
  int srcStride, dstStride, r0, c0;
  if (bid < 768) {
    int mat = bid >> 8;
    int rem = bid & 255;
    int h = rem >> 4, dt = rem & 15;
    const float* W = (mat == 0) ? Wq : (mat == 1) ? Wk : Wv;
    src = W + (size_t)h * (ND * NHS);
    dst = wt + (size_t)mat * WSLAB + (size_t)h * (NHS * ND);
    srcStride = NHS; dstStride = ND;
    r0 = dt * 64; c0 = 0;
  } else {
    int rem = bid - 768;
    int dt = rem >> 4, et = rem & 15;
    src = Wo; dst = wt + 3 * WSLAB;
    srcStride = ND; dstStride = ND;
    r0 = dt * 64; c0 = et * 64;
  }
  for (int u = tid; u < 1024; u += 256) {
    int row = u >> 4, cq = u & 15;
    float4 f = *(const float4*)&src[(size_t)(r0 + row) * srcStride + c0 + cq * 4];
    uint16_t* p = &T[row][cq * 4];
    p[0] = f2b(f.x); p[1] = f2b(f.y); p[2] = f2b(f.z); p[3] = f2b(f.w);
  }
  __syncthreads();
  for (int u = tid; u < 512; u += 256) {
    int c = u >> 3, cg = u & 7;
    __align__(16) uint16_t tmp[8];
    for (int j = 0; j < 8; j++) tmp[j] = T[cg * 8 + j][c];
    *(uint4*)&dst[(size_t)(c0 + c) * dstStride + r0 + cg * 8] = *(uint4*)tmp;
  }
}

// ---------------- kernel 1: fused QKV GEMM, 128x128 m97-style single-phase ----------------
// Round-12: the lock allowed a FUNDAMENTALLY different schedule; this is the m97/r9
// structure: ONE __syncthreads per K-step (vs 4 barriers + 2 counted waits in the 2-phase
// plateau version), 16 MFMA between barriers, 2 full-tile LDS buffers. Step t: issue 4
// gll16 for tile t+1 into buf^1 (its readers retired at end-of-(t-1) barrier); 12
// swizzled ds_read_b128 + 16 MFMA from buf; __syncthreads (intrinsic vmcnt0+lgkm0 drain
// publishes buf^1 and retires buf) — exactly r9's k_attn ledger, m97 measured 874-912 TF
// at this tile/BK. Swizzle (both-sides, rule 21): 8-chunk rows; source chunk pre-XOR'd
// with row&7 ((tid&7)^((tid>>3)&7)); frag reads use chunk (kk*4+quad)^(l16&7) -> 8-pass
// floor (verified: row&7 == l16&7 for all A/B frag rows). MFMA order (kk0 then kk1 into
// same acc) identical to the 2-phase version -> bitwise-same output.
__global__ __launch_bounds__(512, 4) void k_qkv(
    const uint16_t* __restrict__ xb, const uint16_t* __restrict__ wt,
    uint16_t* __restrict__ qk, uint16_t* __restrict__ vt) {
  __shared__ __align__(16) uint16_t L[32768];   // 2 bufs x {A 8192, B 8192} u16 = 64 KB

  int bid = blockIdx.x;
  int xcd = bid & 7, idx = bid >> 3;     // 192 tiles per XCD chunk
  int mtile = xcd * 8 + (idx & 7);       // 8 m-tiles per XCD, inner (2MB A L2-resident)
  int ntile = idx >> 3;                  // 24 n-tiles, outer
  int m0 = mtile * 128;
  int n0 = ntile * 128;

  int tid = threadIdx.x;
  int wave = tid >> 6, lane = tid & 63, quad = lane >> 4, l16 = lane & 15;
  int wr = wave >> 2, wc = wave & 3;

  // staging: thread covers (row = tid>>3 [0..63], chunk = tid&7) of a 128x64 tile half;
  // second gll16 covers rows 64..127. Source chunk pre-swizzled with row&7.
  int swc = ((tid & 7) ^ ((tid >> 3) & 7)) * 8;
  const uint16_t* pA = xb + (size_t)(m0 + (tid >> 3)) * ND + swc;
  const uint16_t* pB = wt + (size_t)(n0 + (tid >> 3)) * ND + swc;
  const int stOff = wave * 512;          // wave-uniform gll16 dest base (u16)

  // frag-read bases (u16); chunk XOR'd with the same key (l16&7)
  int e3 = l16 & 7;
  const int rowA = (wr * 64 + l16) * 64;          // + i*1024
  const int rowB = 8192 + (wc * 32 + l16) * 64;   // + j*1024
  const int ck0 = (quad ^ e3) * 8;                // kk=0 chunk
  const int ck1 = ((4 | quad) ^ e3) * 8;          // kk=1 chunk

  floatx4 acc[4][2];
  #pragma unroll
  for (int i = 0; i < 4; i++)
    #pragma unroll
    for (int j = 0; j < 2; j++) acc[i][j] = (floatx4){0.f, 0.f, 0.f, 0.f};

#define STAGE_T(T, BUF)                                                         \
  do {                                                                          \
    int kb_ = (T) * 64;                                                         \
    int lb_ = (BUF) * 16384;                                                    \
    gll16(pA + kb_, &L[lb_ + stOff]);                                           \
    gll16(pA + 64 * ND + kb_, &L[lb_ + 4096 + stOff]);                          \
    gll16(pB + kb_, &L[lb_ + 8192 + stOff]);                                    \
    gll16(pB + 64 * ND + kb_, &L[lb_ + 12288 + stOff]);                         \
  } while (0)

#define MFMA8()                                                                           \
  _Pragma("unroll")                                                                       \
  for (int mt_ = 0; mt_ < 4; mt_++)                                                       \
    _Pragma("unroll")                                                                     \
    for (int nt_ = 0; nt_ < 2; nt_++)                                                     \
      acc[mt_][nt_] = __builtin_amdgcn_mfma_f32_16x16x32_bf16(af[mt_], bfr[nt_], acc[mt_][nt_], 0, 0, 0)

  // prologue: tile 0 -> buf0; __syncthreads' intrinsic vmcnt(0) waits it
  STAGE_T(0, 0);
  __syncthreads();

  for (int t = 0; t < 16; ++t) {
    int cur = t & 1;
    if (t < 15) STAGE_T(t + 1, cur ^ 1);   // buf^1 free since end-of-step t-1
    const int base = cur * 16384;
    {   // kk = 0
      bf16x8 af[4], bfr[2];
      #pragma unroll
      for (int i = 0; i < 4; i++) af[i] = *(const bf16x8*)&L[base + rowA + i * 1024 + ck0];
      #pragma unroll
      for (int j = 0; j < 2; j++) bfr[j] = *(const bf16x8*)&L[base + rowB + j * 1024 + ck0];
      __builtin_amdgcn_s_setprio(1);
      MFMA8();
      __builtin_amdgcn_s_setprio(0);
    }
    {   // kk = 1
      bf16x8 af[4], bfr[2];
      #pragma unroll
      for (int i = 0; i < 4; i++) af[i] = *(const bf16x8*)&L[base + rowA + i * 1024 + ck1];
      #pragma unroll
      for (int j = 0; j < 2; j++) bfr[j] = *(const bf16x8*)&L[base + rowB + j * 1024 + ck1];
      __builtin_amdgcn_s_setprio(1);
      MFMA8();
      __builtin_amdgcn_s_setprio(0);
    }
    if (t < 15) __syncthreads();   // publishes buf^1 gll16s; retires buf reads
  }
#undef MFMA8
#undef STAGE_T

  // n-decomposition: head hh, element e within head
  int matid = n0 >> 10;
  int b = m0 >> 11;
  if (matid == 2) {
    // ---- V blocks: store V^T ([b,h,e,s]) directly from registers (uint2, s-contiguous) ----
    int hh = ((n0 - 2048) >> 6) + (wc >> 1);
    #pragma unroll
    for (int nt = 0; nt < 2; nt++) {
      int e = (wc & 1) * 32 + nt * 16 + l16;
      uint16_t* vrow = vt + ((size_t)(b * 16 + hh) * 64 + e) * NS;
      #pragma unroll
      for (int mt = 0; mt < 4; mt++) {
        __align__(8) uint16_t t4v[4];
        #pragma unroll
        for (int r = 0; r < 4; r++) t4v[r] = f2b(acc[mt][nt][r]);
        int s = (m0 & 2047) + wr * 64 + mt * 16 + quad * 4;
        *(uint2*)&vrow[s] = *(uint2*)t4v;
      }
    }
  } else {
    // ---- Q/K blocks: scatter to [b,h,s,e] with Q pre-scale ----
    float scale = (matid == 0) ? Q_SCALE : 1.0f;
    uint16_t* base = qk + (size_t)matid * QSLAB;
    int hh = ((n0 & 1023) >> 6) + (wc >> 1);
    #pragma unroll
    for (int mt = 0; mt < 4; mt++) {
      int s = (m0 & 2047) + wr * 64 + mt * 16 + quad * 4;
      size_t rbase = ((size_t)(b * 16 + hh) * NS + s) * NHS;
      #pragma unroll
      for (int nt = 0; nt < 2; nt++)
        #pragma unroll
        for (int r = 0; r < 4; r++)
          base[rbase + (size_t)r * NHS + (wc & 1) * 32 + nt * 16 + l16] =
              f2b(acc[mt][nt][r] * scale);
    }
  }
}

#if HAVE_MFMA1K
// ---------------- kernel 2: causal attention, S^T trick, gll16 staging, 1 barrier/step --
// (round-12 verified: ta-balanced 1D grid, -15us total; keep byte-identical)
__global__ __launch_bounds__(256, 4) void k_attn(
    const uint16_t* __restrict__ Q, const uint16_t* __restrict__ K,
    const uint16_t* __restrict__ VT, uint16_t* __restrict__ Y) {
  __shared__ __align__(16) uint16_t Ks[2][4096];   // [buf][k*64 + swz e-chunk]
  __shared__ __align__(16) uint16_t Vs[2][4096];   // [buf][e*64 + swz key-chunk]
  int bid = blockIdx.x;
  int bh = bid & 63;
  int w = bid >> 6;
  int ta = (w & 8) ? (15 - (w & 7)) : w;   // 0..15, CU-balanced + XCD-local
  int b = bh >> 4, h = bh & 15;
  int tb = 31 - ta;          // 16..31
  const uint16_t* Qp = Q + (size_t)bh * (NS * NHS);
  const uint16_t* Kp = K + (size_t)bh * (NS * NHS);
  const uint16_t* Vp = VT + (size_t)bh * (NS * NHS);  // [e][key]
  int tid = threadIdx.x;
  int wv = tid >> 6, lane = tid & 63, quad = lane >> 4, l16 = lane & 15;

  // gll16 staging map: wave wv covers rows [wv*16, wv*16+16) in two 8-row groups.
  int srow = lane >> 3;                       // row offset in 8-row group (= row&7)
  int swOff = ((lane & 7) ^ srow) * 8;        // pre-swizzled source chunk (u16)
  int stRow0 = wv * 16 + srow;
  int stRow1 = wv * 16 + 8 + srow;
  const int dst0 = wv * 1024;                 // wave-uniform LDS dest (u16)
  const int dst1 = wv * 1024 + 512;

#define STAGE_KV(KT, BUF)                                                         \
  do {                                                                            \
    int kt_ = (KT);                                                               \
    gll16(Kp + (size_t)(kt_ * 64 + stRow0) * NHS + swOff, &Ks[BUF][dst0]);        \
    gll16(Kp + (size_t)(kt_ * 64 + stRow1) * NHS + swOff, &Ks[BUF][dst1]);        \
    gll16(Vp + (size_t)stRow0 * NS + kt_ * 64 + swOff, &Vs[BUF][dst0]);           \
    gll16(Vp + (size_t)stRow1 * NS + kt_ * 64 + swOff, &Vs[BUF][dst1]);           \
  } while (0)

  // swizzled frag-read column offsets (u16 within a 64-u16 row)
  int e3 = l16 & 7;
  int kc0 = (quad ^ e3) * 8;              // kb0: logical chunk quad
  int kc1 = ((4 | quad) ^ e3) * 8;        // kb1: logical chunk 4+quad
  int vql = (quad & 1) * 4;
  int vqh = quad >> 1;
  int vcol[4];
  #pragma unroll
  for (int ct = 0; ct < 4; ct++)
    vcol[ct] = (((ct * 2 + vqh) ^ e3) * 8) + vql;

  // Q fragments from global; B operand of S^T = K.Q^T (n = q-row = l16)
  int rA = ta * 64 + wv * 16 + l16;
  int rB = tb * 64 + wv * 16 + l16;
  bf16x8 aqA0 = *(const bf16x8*)&Qp[(size_t)rA * NHS + quad * 8];
  bf16x8 aqA1 = *(const bf16x8*)&Qp[(size_t)rA * NHS + 32 + quad * 8];
  bf16x8 aqB0 = *(const bf16x8*)&Qp[(size_t)rB * NHS + quad * 8];
  bf16x8 aqB1 = *(const bf16x8*)&Qp[(size_t)rB * NHS + 32 + quad * 8];

  float lAs = 0.f, lBs = 0.f;          // per-lane row-sum (all p of a lane share q-row l16)
  floatx4 oA[4], oB[4];                // O^T accumulators, one per e-tile
  for (int et = 0; et < 4; et++) {
    oA[et] = (floatx4){0.f, 0.f, 0.f, 0.f};
    oB[et] = (floatx4){0.f, 0.f, 0.f, 0.f};
  }

  // prologue: tile 0 -> buf0; __syncthreads' intrinsic vmcnt(0) waits it (and Q loads)
  STAGE_KV(0, 0);
  __syncthreads();

  for (int kt = 0; kt <= tb; kt++) {
    int cur = kt & 1;
    if (kt < tb) STAGE_KV(kt + 1, cur ^ 1);   // buf^1 free since end-of-step kt-1
    const uint16_t* KB = &Ks[cur][0];
    const uint16_t* VB = &Vs[cur][0];
    bool doA = (kt <= ta);  // uniform across block

    // ---- S^T tiles + mask + exp2 + pack (P^T lands in B-layout of K=16 MFMA) ----
    s16x4 pbA[4], pbB[4];
    #pragma unroll
    for (int ct = 0; ct < 4; ct++) {
      int krow = (ct * 16 + l16) * 64;
      bf16x8 kb0 = *(const bf16x8*)&KB[krow + kc0];
      bf16x8 kb1 = *(const bf16x8*)&KB[krow + kc1];
      int key = kt * 64 + ct * 16 + quad * 4;
      floatx4 c = (floatx4){0.f, 0.f, 0.f, 0.f};
      c = __builtin_amdgcn_mfma_f32_16x16x32_bf16(kb0, aqB0, c, 0, 0, 0);
      c = __builtin_amdgcn_mfma_f32_16x16x32_bf16(kb1, aqB1, c, 0, 0, 0);
      #pragma unroll
      for (int r = 0; r < 4; r++) {
        float s = (kt == tb && key + r > rB) ? NEG_BIG : c[r];
        float p = __builtin_amdgcn_exp2f(s);
        lBs += p;
        pbB[ct][r] = (short)f2b(p);
      }
      if (doA) {
        floatx4 d = (floatx4){0.f, 0.f, 0.f, 0.f};
        d = __builtin_amdgcn_mfma_f32_16x16x32_bf16(kb0, aqA0, d, 0, 0, 0);
        d = __builtin_amdgcn_mfma_f32_16x16x32_bf16(kb1, aqA1, d, 0, 0, 0);
        #pragma unroll
        for (int r = 0; r < 4; r++) {
          float s = (kt == ta && key + r > rA) ? NEG_BIG : d[r];
          float p = __builtin_amdgcn_exp2f(s);
          lAs += p;
          pbA[ct][r] = (short)f2b(p);
        }
      }
    }
    // ---- O^T += V^T . P^T (A-frag = 4 keys of V^T via swizzled 8B reads) ----
    #pragma unroll
    for (int et = 0; et < 4; et++) {
      int vrow = (et * 16 + l16) * 64;
      #pragma unroll
      for (int ct = 0; ct < 4; ct++) {
        s16x4 va = *(const s16x4*)&VB[vrow + vcol[ct]];
        oB[et] = __builtin_amdgcn_mfma_f32_16x16x16bf16_1k(va, pbB[ct], oB[et], 0, 0, 0);
        if (doA)
          oA[et] = __builtin_amdgcn_mfma_f32_16x16x16bf16_1k(va, pbA[ct], oA[et], 0, 0, 0);
      }
    }
    __syncthreads();   // publishes buf^1 gll16s (intrinsic vmcnt(0)); retires buf reads
  }
#undef STAGE_KV

  // ---- reduce row-sums across the 4 quads, normalize, packed store ----
  lAs += __shfl_xor(lAs, 16, 64); lAs += __shfl_xor(lAs, 32, 64);
  lBs += __shfl_xor(lBs, 16, 64); lBs += __shfl_xor(lBs, 32, 64);
  float invA = 1.f / lAs, invB = 1.f / lBs;
  uint16_t* yb = Y + (size_t)b * NS * ND + (size_t)h * NHS;
  for (int et = 0; et < 4; et++) {
    __align__(8) uint16_t tA[4], tB[4];
    for (int r = 0; r < 4; r++) {
      tA[r] = f2b(oA[et][r] * invA);
      tB[r] = f2b(oB[et][r] * invB);
    }
    *(uint2*)&yb[(size_t)rA * ND + et * 16 + quad * 4] = *(uint2*)tA;
    *(uint2*)&yb[(size_t)rB * ND + et * 16 + quad * 4] = *(uint2*)tB;
  }
}
#else
// ---------------- fallback: round-8 k_attn (LDS-staged K/V + P round-trip) ----------------
__global__ __launch_bounds__(256) void k_attn(
    const uint16_t* __restrict__ Q, const uint16_t* __restrict__ K,
    const uint16_t* __restrict__ VT, uint16_t* __restrict__ Y) {
  __shared__ __align__(16) uint16_t Ks[64][72];
  __shared__ __align__(16) uint16_t Vs[64][72];
  __shared__ __align__(16) uint16_t Ps[4][2][16][72];
  int bid = blockIdx.x;
  int bh = bid & 63;
  int w = bid >> 6;
  int ta = (w & 8) ? (15 - (w & 7)) : w;
  int b = bh >> 4, h = bh & 15;
  int tb = 31 - ta;
  const uint16_t* Qp = Q + (size_t)bh * (NS * NHS);
  const uint16_t* Kp = K + (size_t)bh * (NS * NHS);
  const uint16_t* Vp = VT + (size_t)bh * (NS * NHS);
  int tid = threadIdx.x;
  int wv = tid >> 6, lane = tid & 63, quad = lane >> 4, l16 = lane & 15;

  int rA = ta * 64 + wv * 16 + l16;
  int rB = tb * 64 + wv * 16 + l16;
  bf16x8 aqA0 = *(const bf16x8*)&Qp[(size_t)rA * NHS + quad * 8];
  bf16x8 aqA1 = *(const bf16x8*)&Qp[(size_t)rA * NHS + 32 + quad * 8];
  bf16x8 aqB0 = *(const bf16x8*)&Qp[(size_t)rB * NHS + quad * 8];
  bf16x8 aqB1 = *(const bf16x8*)&Qp[(size_t)rB * NHS + 32 + quad * 8];

  float lA[4] = {0.f, 0.f, 0.f, 0.f}, lB[4] = {0.f, 0.f, 0.f, 0.f};
  floatx4 oA[4], oB[4];
  for (int ct = 0; ct < 4; ct++) {
    oA[ct] = (floatx4){0.f, 0.f, 0.f, 0.f};
    oB[ct] = (floatx4){0.f, 0.f, 0.f, 0.f};
  }
  for (int kt = 0; kt <= tb; kt++) {
    bool doA = (kt <= ta);
    __syncthreads();
    for (int u = tid; u < 512; u += 256) {
      int row = u >> 3, cg = u & 7;
      *(uint4*)&Ks[row][cg * 8] =
          *(const uint4*)&Kp[(size_t)(kt * 64 + row) * NHS + cg * 8];
    }
    for (int u = tid; u < 512; u += 256) {
      int row = u >> 3, cg = u & 7;
      *(uint4*)&Vs[row][cg * 8] =
          *(const uint4*)&Vp[(size_t)row * NS + kt * 64 + cg * 8];
    }
    __syncthreads();
    floatx4 sA[4], sB[4];
    for (int ct = 0; ct < 4; ct++) {
      bf16x8 kb0 = *(const bf16x8*)&Ks[ct * 16 + l16][quad * 8];
      bf16x8 kb1 = *(const bf16x8*)&Ks[ct * 16 + l16][32 + quad * 8];
      floatx4 c = (floatx4){0.f, 0.f, 0.f, 0.f};
      c = __builtin_amdgcn_mfma_f32_16x16x32_bf16(aqB0, kb0, c, 0, 0, 0);
      c = __builtin_amdgcn_mfma_f32_16x16x32_bf16(aqB1, kb1, c, 0, 0, 0);
      sB[ct] = c;
      if (doA) {
        floatx4 d = (floatx4){0.f, 0.f, 0.f, 0.f};
        d = __builtin_amdgcn_mfma_f32_16x16x32_bf16(aqA0, kb0, d, 0, 0, 0);
        d = __builtin_amdgcn_mfma_f32_16x16x32_bf16(aqA1, kb1, d, 0, 0, 0);
        sA[ct] = d;
      }
    }
    if (kt == tb) {
      int qrb = tb * 64 + wv * 16 + quad * 4;
      for (int ct = 0; ct < 4; ct++) {
        int kg = kt * 64 + ct * 16 + l16;
        for (int r = 0; r < 4; r++)
          sB[ct][r] = (kg <= qrb + r) ? sB[ct][r] : NEG_BIG;
      }
    }
    if (doA && kt == ta) {
      int qrb = ta * 64 + wv * 16 + quad * 4;
      for (int ct = 0; ct < 4; ct++) {
        int kg = kt * 64 + ct * 16 + l16;
        for (int r = 0; r < 4; r++)
          sA[ct][r] = (kg <= qrb + r) ? sA[ct][r] : NEG_BIG;
      }
    }
    for (int ct = 0; ct < 4; ct++)
      for (int r = 0; r < 4; r++) {
        float p = __builtin_amdgcn_exp2f(sB[ct][r]);
        lB[r] += p;
        Ps[wv][1][quad * 4 + r][ct * 16 + l16] = f2b(p);
      }
    if (doA)
      for (int ct = 0; ct < 4; ct++)
        for (int r = 0; r < 4; r++) {
          float p = __builtin_amdgcn_exp2f(sA[ct][r]);
          lA[r] += p;
          Ps[wv][0][quad * 4 + r][ct * 16 + l16] = f2b(p);
        }
    bf16x8 apB0 = *(const bf16x8*)&Ps[wv][1][l16][quad * 8];
    bf16x8 apB1 = *(const bf16x8*)&Ps[wv][1][l16][32 + quad * 8];
    bf16x8 apA0, apA1;
    if (doA) {
      apA0 = *(const bf16x8*)&Ps[wv][0][l16][quad * 8];
      apA1 = *(const bf16x8*)&Ps[wv][0][l16][32 + quad * 8];
    }
    for (int ct = 0; ct < 4; ct++) {
      bf16x8 vb0 = *(const bf16x8*)&Vs[ct * 16 + l16][quad * 8];
      bf16x8 vb1 = *(const bf16x8*)&Vs[ct * 16 + l16][32 + quad * 8];
      oB[ct] = __builtin_amdgcn_mfma_f32_16x16x32_bf16(apB0, vb0, oB[ct], 0, 0, 0);
      oB[ct] = __builtin_amdgcn_mfma_f32_16x16x32_bf16(apB1, vb1, oB[ct], 0, 0, 0);
      if (doA) {
        oA[ct] = __builtin_amdgcn_mfma_f32_16x16x32_bf16(apA0, vb0, oA[ct], 0, 0, 0);
        oA[ct] = __builtin_amdgcn_mfma_f32_16x16x32_bf16(apA1, vb1, oA[ct], 0, 0, 0);
      }
    }
  }
  for (int off = 1; off < 16; off <<= 1)
    for (int r = 0; r < 4; r++) {
      lA[r] += __shfl_xor(lA[r], off, 64);
      lB[r] += __shfl_xor(lB[r], off, 64);
    }
  uint16_t* yb = Y + (size_t)b * NS * ND + (size_t)h * NHS;
  for (int ct = 0; ct < 4; ct++)
    for (int r = 0; r < 4; r++) {
      int sA_ = ta * 64 + wv * 16 + quad * 4 + r;
      int sB_ = tb * 64 + wv * 16 + quad * 4 + r;
      yb[(size_t)sA_ * ND + ct * 16 + l16] = f2b(oA[ct][r] / lA[r]);
      yb[(size_t)sB_ * ND + ct * 16 + l16] = f2b(oB[ct][r] / lB[r]);
    }
}
#endif

// ---------------- kernel 3: output projection + bias, m97-style single-phase ----------
// (same round-12 schedule transformation as k_qkv; epilogue fp32 + bias unchanged)
__global__ __launch_bounds__(512, 4) void k_proj(
    const uint16_t* __restrict__ y, const uint16_t* __restrict__ wot,
    const float* __restrict__ bo, float* __restrict__ out) {
  __shared__ __align__(16) uint16_t L[32768];   // 2 bufs x {A 8192, B 8192} u16

  int bid = blockIdx.x;
  int xcd = bid & 7, idx = bid >> 3;     // 64 tiles per XCD chunk
  int mtile = xcd * 8 + (idx & 7);       // 8 m-tiles per XCD, inner
  int ntile = idx >> 3;                  // 8 n-tiles, outer
  int m0 = mtile * 128;
  int n0 = ntile * 128;

  int tid = threadIdx.x;
  int wave = tid >> 6, lane = tid & 63, quad = lane >> 4, l16 = lane & 15;
  int wr = wave >> 2, wc = wave & 3;

  int swc = ((tid & 7) ^ ((tid >> 3) & 7)) * 8;
  const uint16_t* pA = y + (size_t)(m0 + (tid >> 3)) * ND + swc;
  const uint16_t* pB = wot + (size_t)(n0 + (tid >> 3)) * ND + swc;
  const int stOff = wave * 512;

  int e3 = l16 & 7;
  const int rowA = (wr * 64 + l16) * 64;
  const int rowB = 8192 + (wc * 32 + l16) * 64;
  const int ck0 = (quad ^ e3) * 8;
  const int ck1 = ((4 | quad) ^ e3) * 8;

  floatx4 acc[4][2];
  #pragma unroll
  for (int i = 0; i < 4; i++)
    #pragma unroll
    for (int j = 0; j < 2; j++) acc[i][j] = (floatx4){0.f, 0.f, 0.f, 0.f};

#define STAGE_T(T, BUF)                                                         \
  do {                                                                          \
    int kb_ = (T) * 64;                                                         \
    int lb_ = (BUF) * 16384;                                                    \
    gll16(pA + kb_, &L[lb_ + stOff]);                                           \
    gll16(pA + 64 * ND + kb_, &L[lb_ + 4096 + stOff]);                          \
    gll16(pB + kb_, &L[lb_ + 8192 + stOff]);                                    \
    gll16(pB + 64 * ND + kb_, &L[lb_ + 12288 + stOff]);                         \
  } while (0)

#define MFMA8()                                                                           \
  _Pragma("unroll")                                                                       \
  for (int mt_ = 0; mt_ < 4; mt_++)                                                       \
    _Pragma("unroll")                                                                     \
    for (int nt_ = 0; nt_ < 2; nt_++)                                                     \
      acc[mt_][nt_] = __builtin_amdgcn_mfma_f32_16x16x32_bf16(af[mt_], bfr[nt_], acc[mt_][nt_], 0, 0, 0)

  STAGE_T(0, 0);
  __syncthreads();

  for (int t = 0; t < 16; ++t) {
    int cur = t & 1;
    if (t < 15) STAGE_T(t + 1, cur ^ 1);
    const int base = cur * 16384;
    {   // kk = 0
      bf16x8 af[4], bfr[2];
      #pragma unroll
      for (int i = 0; i < 4; i++) af[i] = *(const bf16x8*)&L[base + rowA + i * 1024 + ck0];
      #pragma unroll
      for (int j = 0; j < 2; j++) bfr[j] = *(const bf16x8*)&L[base + rowB + j * 1024 + ck0];
      __builtin_amdgcn_s_setprio(1);
      MFMA8();
      __builtin_amdgcn_s_setprio(0);
    }
    {   // kk = 1
      bf16x8 af[4], bfr[2];
      #pragma unroll
      for (int i = 0; i < 4; i++) af[i] = *(const bf16x8*)&L[base + rowA + i * 1024 + ck1];
      #pragma unroll
      for (int j = 0; j < 2; j++) bfr[j] = *(const bf16x8*)&L[base + rowB + j * 1024 + ck1];
      __builtin_amdgcn_s_setprio(1);
      MFMA8();
      __builtin_amdgcn_s_setprio(0);
    }
    if (t < 15) __syncthreads();
  }
#undef MFMA8
#undef STAGE_T

  // epilogue: fp32 out + bias (col n = n0 + wc*32 + nt*16 + l16)
  float bv[2];
  #pragma unroll
  for (int nt = 0; nt < 2; nt++) bv[nt] = bo[n0 + wc * 32 + nt * 16 + l16];
  #pragma unroll
  for (int mt = 0; mt < 4; mt++) {
    int s = m0 + wr * 64 + mt * 16 + quad * 4;
    #pragma unroll
    for (int nt = 0; nt < 2; nt++) {
      int n = n0 + wc * 32 + nt * 16 + l16;
      #pragma unroll
      for (int r = 0; r < 4; r++)
        out[(size_t)(s + r) * ND + n] = acc[mt][nt][r] + bv[nt];
    }
  }
}

extern "C" void kernel_launch(void* const* d_in, const int* in_sizes, int n_in,
                              void* d_out, int out_size, void* d_ws, size_t ws_size,
                              hipStream_t stream) {
  const float* x  = (const float*)d_in[0];
  const float* Wq = (const float*)d_in[1];
  const float* Wk = (const float*)d_in[2];
  const float* Wv = (const float*)d_in[3];
  const float* Wo = (const float*)d_in[4];
  const float* bo = (const float*)d_in[5];
  uint16_t* ws = (uint16_t*)d_ws;

  uint16_t* wt = ws;                       // 4 * WSLAB bf16 (Wq_t, Wk_t, Wv_t, Wo_t)
  uint16_t* xb = ws + 4 * WSLAB;           // XSLAB bf16
  uint16_t* q  = xb + XSLAB;               // QSLAB each; k contiguous after q
  uint16_t* k  = q + QSLAB;
  uint16_t* vt = k + QSLAB;                // QSLAB (V transposed, written by k_qkv)
  uint16_t* y  = vt + QSLAB;

  k_prep<<<dim3(5120), dim3(256), 0, stream>>>(x, Wq, Wk, Wv, Wo, xb, wt);
  k_qkv<<<dim3(1536), dim3(512), 0, stream>>>(xb, wt, q, vt);
  k_attn<<<dim3(1024), dim3(256), 0, stream>>>(q, k, vt, y);
  k_proj<<<dim3(512), dim3(512), 0, stream>>>(y, wt + 3 * WSLAB, bo, (float*)d_out);
}

// Round 14
// 218.085 us; speedup vs baseline: 1.1652x; 1.0494x over previous
//
#include <hip/hip_runtime.h>
#include <hip/hip_bf16.h>
#include <stdint.h>

#define NB 4
#define NS 2048
#define ND 1024
#define NH 16
#define NHS 64
#define NEG_BIG (-1e30f)
// 1/sqrt(HS) * log2(e): folds softmax exp->exp2 into Q scaling (exactly softmax-invariant)
#define Q_SCALE 0.18033688011112042f

typedef __bf16 bf16x8 __attribute__((ext_vector_type(8)));
typedef float floatx4 __attribute__((ext_vector_type(4)));
typedef short s16x4 __attribute__((ext_vector_type(4)));

#if defined(__has_builtin)
#if __has_builtin(__builtin_amdgcn_mfma_f32_16x16x16bf16_1k)
#define HAVE_MFMA1K 1
#endif
#endif
#ifndef HAVE_MFMA1K
#define HAVE_MFMA1K 0
#endif

static constexpr size_t WSLAB = (size_t)NH * ND * NHS;        // 2^20 elems per weight mat
static constexpr size_t QSLAB = (size_t)NB * NH * NS * NHS;   // 8M elems per QKV/Y slab
static constexpr size_t XSLAB = (size_t)NB * NS * ND;         // 8M elems (x as bf16)

__device__ __forceinline__ uint16_t f2b(float f) {
    union { __hip_bfloat16 h; uint16_t u; } cv;
    cv.h = __float2bfloat16(f);
    return cv.u;
}

// async global->LDS, 16B per lane. LDS dest = wave-uniform base + lane*16 (UNPADDED only).
__device__ __forceinline__ void gll16(const void* g, void* l) {
  __builtin_amdgcn_global_load_lds(
      (__attribute__((address_space(1))) void*)(uintptr_t)g,
      (__attribute__((address_space(3))) void*)(uintptr_t)l,
      16, 0, 0);
}

// ---------------- kernel P: merged x-convert + weight convert/transpose ----------------
__global__ __launch_bounds__(256) void k_prep(
    const float* __restrict__ x, const float* __restrict__ Wq,
    const float* __restrict__ Wk, const float* __restrict__ Wv,
    const float* __restrict__ Wo, uint16_t* __restrict__ xb,
    uint16_t* __restrict__ wt) {
  __shared__ __align__(16) uint16_t T[64][72];
  int bid = blockIdx.x;
  int tid = threadIdx.x;
  if (bid < 4096) {
    size_t i0 = ((size_t)bid * 256 + tid) * 8;
    float4 f0 = *(const float4*)&x[i0];
    float4 f1 = *(const float4*)&x[i0 + 4];
    __align__(16) uint16_t tmp[8];
    tmp[0] = f2b(f0.x); tmp[1] = f2b(f0.y); tmp[2] = f2b(f0.z); tmp[3] = f2b(f0.w);
    tmp[4] = f2b(f1.x); tmp[5] = f2b(f1.y); tmp[6] = f2b(f1.z); tmp[7] = f2b(f1.w);
    *(uint4*)&xb[i0] = *(uint4*)tmp;
    return;
  }
  bid -= 4096;
  const float* src; uint16_t* dst;
  int srcStride, dstStride, r0, c0;
  if (bid < 768) {
    int mat = bid >> 8;
    int rem = bid & 255;
    int h = rem >> 4, dt = rem & 15;
    const float* W = (mat == 0) ? Wq : (mat == 1) ? Wk : Wv;
    src = W + (size_t)h * (ND * NHS);
    dst = wt + (size_t)mat * WSLAB + (size_t)h * (NHS * ND);
    srcStride = NHS; dstStride = ND;
    r0 = dt * 64; c0 = 0;
  } else {
    int rem = bid - 768;
    int dt = rem >> 4, et = rem & 15;
    src = Wo; dst = wt + 3 * WSLAB;
    srcStride = ND; dstStride = ND;
    r0 = dt * 64; c0 = et * 64;
  }
  for (int u = tid; u < 1024; u += 256) {
    int row = u >> 4, cq = u & 15;
    float4 f = *(const float4*)&src[(size_t)(r0 + row) * srcStride + c0 + cq * 4];
    uint16_t* p = &T[row][cq * 4];
    p[0] = f2b(f.x); p[1] = f2b(f.y); p[2] = f2b(f.z); p[3] = f2b(f.w);
  }
  __syncthreads();
  for (int u = tid; u < 512; u += 256) {
    int c = u >> 3, cg = u & 7;
    __align__(16) uint16_t tmp[8];
    for (int j = 0; j < 8; j++) tmp[j] = T[cg * 8 + j][c];
    *(uint4*)&dst[(size_t)(c0 + c) * dstStride + r0 + cg * 8] = *(uint4*)tmp;
  }
}

// ---------------- kernel 1: fused QKV GEMM, 128x128 m97-style single-phase ----------------
// (round-13 verified: dropped out of top-5, ~850+ TF; the single-barrier full-tile-dbuf
// schedule beat the 2-phase plateau by ~10 us. LOCKED.)
__global__ __launch_bounds__(512, 4) void k_qkv(
    const uint16_t* __restrict__ xb, const uint16_t* __restrict__ wt,
    uint16_t* __restrict__ qk, uint16_t* __restrict__ vt) {
  __shared__ __align__(16) uint16_t L[32768];   // 2 bufs x {A 8192, B 8192} u16 = 64 KB

  int bid = blockIdx.x;
  int xcd = bid & 7, idx = bid >> 3;     // 192 tiles per XCD chunk
  int mtile = xcd * 8 + (idx & 7);       // 8 m-tiles per XCD, inner (2MB A L2-resident)
  int ntile = idx >> 3;                  // 24 n-tiles, outer
  int m0 = mtile * 128;
  int n0 = ntile * 128;

  int tid = threadIdx.x;
  int wave = tid >> 6, lane = tid & 63, quad = lane >> 4, l16 = lane & 15;
  int wr = wave >> 2, wc = wave & 3;

  // staging: thread covers (row = tid>>3 [0..63], chunk = tid&7) of a 128x64 tile half;
  // second gll16 covers rows 64..127. Source chunk pre-swizzled with row&7.
  int swc = ((tid & 7) ^ ((tid >> 3) & 7)) * 8;
  const uint16_t* pA = xb + (size_t)(m0 + (tid >> 3)) * ND + swc;
  const uint16_t* pB = wt + (size_t)(n0 + (tid >> 3)) * ND + swc;
  const int stOff = wave * 512;          // wave-uniform gll16 dest base (u16)

  // frag-read bases (u16); chunk XOR'd with the same key (l16&7)
  int e3 = l16 & 7;
  const int rowA = (wr * 64 + l16) * 64;          // + i*1024
  const int rowB = 8192 + (wc * 32 + l16) * 64;   // + j*1024
  const int ck0 = (quad ^ e3) * 8;                // kk=0 chunk
  const int ck1 = ((4 | quad) ^ e3) * 8;          // kk=1 chunk

  floatx4 acc[4][2];
  #pragma unroll
  for (int i = 0; i < 4; i++)
    #pragma unroll
    for (int j = 0; j < 2; j++) acc[i][j] = (floatx4){0.f, 0.f, 0.f, 0.f};

#define STAGE_T(T, BUF)                                                         \
  do {                                                                          \
    int kb_ = (T) * 64;                                                         \
    int lb_ = (BUF) * 16384;                                                    \
    gll16(pA + kb_, &L[lb_ + stOff]);                                           \
    gll16(pA + 64 * ND + kb_, &L[lb_ + 4096 + stOff]);                          \
    gll16(pB + kb_, &L[lb_ + 8192 + stOff]);                                    \
    gll16(pB + 64 * ND + kb_, &L[lb_ + 12288 + stOff]);                         \
  } while (0)

#define MFMA8()                                                                           \
  _Pragma("unroll")                                                                       \
  for (int mt_ = 0; mt_ < 4; mt_++)                                                       \
    _Pragma("unroll")                                                                     \
    for (int nt_ = 0; nt_ < 2; nt_++)                                                     \
      acc[mt_][nt_] = __builtin_amdgcn_mfma_f32_16x16x32_bf16(af[mt_], bfr[nt_], acc[mt_][nt_], 0, 0, 0)

  // prologue: tile 0 -> buf0; __syncthreads' intrinsic vmcnt(0) waits it
  STAGE_T(0, 0);
  __syncthreads();

  for (int t = 0; t < 16; ++t) {
    int cur = t & 1;
    if (t < 15) STAGE_T(t + 1, cur ^ 1);   // buf^1 free since end-of-step t-1
    const int base = cur * 16384;
    {   // kk = 0
      bf16x8 af[4], bfr[2];
      #pragma unroll
      for (int i = 0; i < 4; i++) af[i] = *(const bf16x8*)&L[base + rowA + i * 1024 + ck0];
      #pragma unroll
      for (int j = 0; j < 2; j++) bfr[j] = *(const bf16x8*)&L[base + rowB + j * 1024 + ck0];
      __builtin_amdgcn_s_setprio(1);
      MFMA8();
      __builtin_amdgcn_s_setprio(0);
    }
    {   // kk = 1
      bf16x8 af[4], bfr[2];
      #pragma unroll
      for (int i = 0; i < 4; i++) af[i] = *(const bf16x8*)&L[base + rowA + i * 1024 + ck1];
      #pragma unroll
      for (int j = 0; j < 2; j++) bfr[j] = *(const bf16x8*)&L[base + rowB + j * 1024 + ck1];
      __builtin_amdgcn_s_setprio(1);
      MFMA8();
      __builtin_amdgcn_s_setprio(0);
    }
    if (t < 15) __syncthreads();   // publishes buf^1 gll16s; retires buf reads
  }
#undef MFMA8
#undef STAGE_T

  // n-decomposition: head hh, element e within head
  int matid = n0 >> 10;
  int b = m0 >> 11;
  if (matid == 2) {
    // ---- V blocks: store V^T ([b,h,e,s]) directly from registers (uint2, s-contiguous) ----
    int hh = ((n0 - 2048) >> 6) + (wc >> 1);
    #pragma unroll
    for (int nt = 0; nt < 2; nt++) {
      int e = (wc & 1) * 32 + nt * 16 + l16;
      uint16_t* vrow = vt + ((size_t)(b * 16 + hh) * 64 + e) * NS;
      #pragma unroll
      for (int mt = 0; mt < 4; mt++) {
        __align__(8) uint16_t t4v[4];
        #pragma unroll
        for (int r = 0; r < 4; r++) t4v[r] = f2b(acc[mt][nt][r]);
        int s = (m0 & 2047) + wr * 64 + mt * 16 + quad * 4;
        *(uint2*)&vrow[s] = *(uint2*)t4v;
      }
    }
  } else {
    // ---- Q/K blocks: scatter to [b,h,s,e] with Q pre-scale ----
    float scale = (matid == 0) ? Q_SCALE : 1.0f;
    uint16_t* base = qk + (size_t)matid * QSLAB;
    int hh = ((n0 & 1023) >> 6) + (wc >> 1);
    #pragma unroll
    for (int mt = 0; mt < 4; mt++) {
      int s = (m0 & 2047) + wr * 64 + mt * 16 + quad * 4;
      size_t rbase = ((size_t)(b * 16 + hh) * NS + s) * NHS;
      #pragma unroll
      for (int nt = 0; nt < 2; nt++)
        #pragma unroll
        for (int r = 0; r < 4; r++)
          base[rbase + (size_t)r * NHS + (wc & 1) * 32 + nt * 16 + l16] =
              f2b(acc[mt][nt][r] * scale);
    }
  }
}

#if HAVE_MFMA1K
// ---------------- kernel 2: causal attention, S^T trick, gll16 staging, 1 barrier/step --
// Round-13 change: T5 s_setprio(1)/(0) around the QK^T and PV MFMA clusters (catalog
// m191: +4-7% on attn in the independent-blocks-per-CU regime, which this kernel is in:
// 4 unsynchronized blocks/CU, MfmaUtil 34 + VALUBusy 47 = 81% issue). No other change.
__global__ __launch_bounds__(256, 4) void k_attn(
    const uint16_t* __restrict__ Q, const uint16_t* __restrict__ K,
    const uint16_t* __restrict__ VT, uint16_t* __restrict__ Y) {
  __shared__ __align__(16) uint16_t Ks[2][4096];   // [buf][k*64 + swz e-chunk]
  __shared__ __align__(16) uint16_t Vs[2][4096];   // [buf][e*64 + swz key-chunk]
  int bid = blockIdx.x;
  int bh = bid & 63;
  int w = bid >> 6;
  int ta = (w & 8) ? (15 - (w & 7)) : w;   // 0..15, CU-balanced + XCD-local
  int b = bh >> 4, h = bh & 15;
  int tb = 31 - ta;          // 16..31
  const uint16_t* Qp = Q + (size_t)bh * (NS * NHS);
  const uint16_t* Kp = K + (size_t)bh * (NS * NHS);
  const uint16_t* Vp = VT + (size_t)bh * (NS * NHS);  // [e][key]
  int tid = threadIdx.x;
  int wv = tid >> 6, lane = tid & 63, quad = lane >> 4, l16 = lane & 15;

  // gll16 staging map: wave wv covers rows [wv*16, wv*16+16) in two 8-row groups.
  int srow = lane >> 3;                       // row offset in 8-row group (= row&7)
  int swOff = ((lane & 7) ^ srow) * 8;        // pre-swizzled source chunk (u16)
  int stRow0 = wv * 16 + srow;
  int stRow1 = wv * 16 + 8 + srow;
  const int dst0 = wv * 1024;                 // wave-uniform LDS dest (u16)
  const int dst1 = wv * 1024 + 512;

#define STAGE_KV(KT, BUF)                                                         \
  do {                                                                            \
    int kt_ = (KT);                                                               \
    gll16(Kp + (size_t)(kt_ * 64 + stRow0) * NHS + swOff, &Ks[BUF][dst0]);        \
    gll16(Kp + (size_t)(kt_ * 64 + stRow1) * NHS + swOff, &Ks[BUF][dst1]);        \
    gll16(Vp + (size_t)stRow0 * NS + kt_ * 64 + swOff, &Vs[BUF][dst0]);           \
    gll16(Vp + (size_t)stRow1 * NS + kt_ * 64 + swOff, &Vs[BUF][dst1]);           \
  } while (0)

  // swizzled frag-read column offsets (u16 within a 64-u16 row)
  int e3 = l16 & 7;
  int kc0 = (quad ^ e3) * 8;              // kb0: logical chunk quad
  int kc1 = ((4 | quad) ^ e3) * 8;        // kb1: logical chunk 4+quad
  int vql = (quad & 1) * 4;
  int vqh = quad >> 1;
  int vcol[4];
  #pragma unroll
  for (int ct = 0; ct < 4; ct++)
    vcol[ct] = (((ct * 2 + vqh) ^ e3) * 8) + vql;

  // Q fragments from global; B operand of S^T = K.Q^T (n = q-row = l16)
  int rA = ta * 64 + wv * 16 + l16;
  int rB = tb * 64 + wv * 16 + l16;
  bf16x8 aqA0 = *(const bf16x8*)&Qp[(size_t)rA * NHS + quad * 8];
  bf16x8 aqA1 = *(const bf16x8*)&Qp[(size_t)rA * NHS + 32 + quad * 8];
  bf16x8 aqB0 = *(const bf16x8*)&Qp[(size_t)rB * NHS + quad * 8];
  bf16x8 aqB1 = *(const bf16x8*)&Qp[(size_t)rB * NHS + 32 + quad * 8];

  float lAs = 0.f, lBs = 0.f;          // per-lane row-sum (all p of a lane share q-row l16)
  floatx4 oA[4], oB[4];                // O^T accumulators, one per e-tile
  for (int et = 0; et < 4; et++) {
    oA[et] = (floatx4){0.f, 0.f, 0.f, 0.f};
    oB[et] = (floatx4){0.f, 0.f, 0.f, 0.f};
  }

  // prologue: tile 0 -> buf0; __syncthreads' intrinsic vmcnt(0) waits it (and Q loads)
  STAGE_KV(0, 0);
  __syncthreads();

  for (int kt = 0; kt <= tb; kt++) {
    int cur = kt & 1;
    if (kt < tb) STAGE_KV(kt + 1, cur ^ 1);   // buf^1 free since end-of-step kt-1
    const uint16_t* KB = &Ks[cur][0];
    const uint16_t* VB = &Vs[cur][0];
    bool doA = (kt <= ta);  // uniform across block

    // ---- S^T tiles + mask + exp2 + pack (P^T lands in B-layout of K=16 MFMA) ----
    s16x4 pbA[4], pbB[4];
    #pragma unroll
    for (int ct = 0; ct < 4; ct++) {
      int krow = (ct * 16 + l16) * 64;
      bf16x8 kb0 = *(const bf16x8*)&KB[krow + kc0];
      bf16x8 kb1 = *(const bf16x8*)&KB[krow + kc1];
      int key = kt * 64 + ct * 16 + quad * 4;
      floatx4 c = (floatx4){0.f, 0.f, 0.f, 0.f};
      __builtin_amdgcn_s_setprio(1);
      c = __builtin_amdgcn_mfma_f32_16x16x32_bf16(kb0, aqB0, c, 0, 0, 0);
      c = __builtin_amdgcn_mfma_f32_16x16x32_bf16(kb1, aqB1, c, 0, 0, 0);
      __builtin_amdgcn_s_setprio(0);
      #pragma unroll
      for (int r = 0; r < 4; r++) {
        float s = (kt == tb && key + r > rB) ? NEG_BIG : c[r];
        float p = __builtin_amdgcn_exp2f(s);
        lBs += p;
        pbB[ct][r] = (short)f2b(p);
      }
      if (doA) {
        floatx4 d = (floatx4){0.f, 0.f, 0.f, 0.f};
        __builtin_amdgcn_s_setprio(1);
        d = __builtin_amdgcn_mfma_f32_16x16x32_bf16(kb0, aqA0, d, 0, 0, 0);
        d = __builtin_amdgcn_mfma_f32_16x16x32_bf16(kb1, aqA1, d, 0, 0, 0);
        __builtin_amdgcn_s_setprio(0);
        #pragma unroll
        for (int r = 0; r < 4; r++) {
          float s = (kt == ta && key + r > rA) ? NEG_BIG : d[r];
          float p = __builtin_amdgcn_exp2f(s);
          lAs += p;
          pbA[ct][r] = (short)f2b(p);
        }
      }
    }
    // ---- O^T += V^T . P^T (A-frag = 4 keys of V^T via swizzled 8B reads) ----
    __builtin_amdgcn_s_setprio(1);
    #pragma unroll
    for (int et = 0; et < 4; et++) {
      int vrow = (et * 16 + l16) * 64;
      #pragma unroll
      for (int ct = 0; ct < 4; ct++) {
        s16x4 va = *(const s16x4*)&VB[vrow + vcol[ct]];
        oB[et] = __builtin_amdgcn_mfma_f32_16x16x16bf16_1k(va, pbB[ct], oB[et], 0, 0, 0);
        if (doA)
          oA[et] = __builtin_amdgcn_mfma_f32_16x16x16bf16_1k(va, pbA[ct], oA[et], 0, 0, 0);
      }
    }
    __builtin_amdgcn_s_setprio(0);
    __syncthreads();   // publishes buf^1 gll16s (intrinsic vmcnt(0)); retires buf reads
  }
#undef STAGE_KV

  // ---- reduce row-sums across the 4 quads, normalize, packed store ----
  lAs += __shfl_xor(lAs, 16, 64); lAs += __shfl_xor(lAs, 32, 64);
  lBs += __shfl_xor(lBs, 16, 64); lBs += __shfl_xor(lBs, 32, 64);
  float invA = 1.f / lAs, invB = 1.f / lBs;
  uint16_t* yb = Y + (size_t)b * NS * ND + (size_t)h * NHS;
  for (int et = 0; et < 4; et++) {
    __align__(8) uint16_t tA[4], tB[4];
    for (int r = 0; r < 4; r++) {
      tA[r] = f2b(oA[et][r] * invA);
      tB[r] = f2b(oB[et][r] * invB);
    }
    *(uint2*)&yb[(size_t)rA * ND + et * 16 + quad * 4] = *(uint2*)tA;
    *(uint2*)&yb[(size_t)rB * ND + et * 16 + quad * 4] = *(uint2*)tB;
  }
}
#else
// ---------------- fallback: round-8 k_attn (LDS-staged K/V + P round-trip) ----------------
__global__ __launch_bounds__(256) void k_attn(
    const uint16_t* __restrict__ Q, const uint16_t* __restrict__ K,
    const uint16_t* __restrict__ VT, uint16_t* __restrict__ Y) {
  __shared__ __align__(16) uint16_t Ks[64][72];
  __shared__ __align__(16) uint16_t Vs[64][72];
  __shared__ __align__(16) uint16_t Ps[4][2][16][72];
  int bid = blockIdx.x;
  int bh = bid & 63;
  int w = bid >> 6;
  int ta = (w & 8) ? (15 - (w & 7)) : w;
  int b = bh >> 4, h = bh & 15;
  int tb = 31 - ta;
  const uint16_t* Qp = Q + (size_t)bh * (NS * NHS);
  const uint16_t* Kp = K + (size_t)bh * (NS * NHS);
  const uint16_t* Vp = VT + (size_t)bh * (NS * NHS);
  int tid = threadIdx.x;
  int wv = tid >> 6, lane = tid & 63, quad = lane >> 4, l16 = lane & 15;

  int rA = ta * 64 + wv * 16 + l16;
  int rB = tb * 64 + wv * 16 + l16;
  bf16x8 aqA0 = *(const bf16x8*)&Qp[(size_t)rA * NHS + quad * 8];
  bf16x8 aqA1 = *(const bf16x8*)&Qp[(size_t)rA * NHS + 32 + quad * 8];
  bf16x8 aqB0 = *(const bf16x8*)&Qp[(size_t)rB * NHS + quad * 8];
  bf16x8 aqB1 = *(const bf16x8*)&Qp[(size_t)rB * NHS + 32 + quad * 8];

  float lA[4] = {0.f, 0.f, 0.f, 0.f}, lB[4] = {0.f, 0.f, 0.f, 0.f};
  floatx4 oA[4], oB[4];
  for (int ct = 0; ct < 4; ct++) {
    oA[ct] = (floatx4){0.f, 0.f, 0.f, 0.f};
    oB[ct] = (floatx4){0.f, 0.f, 0.f, 0.f};
  }
  for (int kt = 0; kt <= tb; kt++) {
    bool doA = (kt <= ta);
    __syncthreads();
    for (int u = tid; u < 512; u += 256) {
      int row = u >> 3, cg = u & 7;
      *(uint4*)&Ks[row][cg * 8] =
          *(const uint4*)&Kp[(size_t)(kt * 64 + row) * NHS + cg * 8];
    }
    for (int u = tid; u < 512; u += 256) {
      int row = u >> 3, cg = u & 7;
      *(uint4*)&Vs[row][cg * 8] =
          *(const uint4*)&Vp[(size_t)row * NS + kt * 64 + cg * 8];
    }
    __syncthreads();
    floatx4 sA[4], sB[4];
    for (int ct = 0; ct < 4; ct++) {
      bf16x8 kb0 = *(const bf16x8*)&Ks[ct * 16 + l16][quad * 8];
      bf16x8 kb1 = *(const bf16x8*)&Ks[ct * 16 + l16][32 + quad * 8];
      floatx4 c = (floatx4){0.f, 0.f, 0.f, 0.f};
      c = __builtin_amdgcn_mfma_f32_16x16x32_bf16(aqB0, kb0, c, 0, 0, 0);
      c = __builtin_amdgcn_mfma_f32_16x16x32_bf16(aqB1, kb1, c, 0, 0, 0);
      sB[ct] = c;
      if (doA) {
        floatx4 d = (floatx4){0.f, 0.f, 0.f, 0.f};
        d = __builtin_amdgcn_mfma_f32_16x16x32_bf16(aqA0, kb0, d, 0, 0, 0);
        d = __builtin_amdgcn_mfma_f32_16x16x32_bf16(aqA1, kb1, d, 0, 0, 0);
        sA[ct] = d;
      }
    }
    if (kt == tb) {
      int qrb = tb * 64 + wv * 16 + quad * 4;
      for (int ct = 0; ct < 4; ct++) {
        int kg = kt * 64 + ct * 16 + l16;
        for (int r = 0; r < 4; r++)
          sB[ct][r] = (kg <= qrb + r) ? sB[ct][r] : NEG_BIG;
      }
    }
    if (doA && kt == ta) {
      int qrb = ta * 64 + wv * 16 + quad * 4;
      for (int ct = 0; ct < 4; ct++) {
        int kg = kt * 64 + ct * 16 + l16;
        for (int r = 0; r < 4; r++)
          sA[ct][r] = (kg <= qrb + r) ? sA[ct][r] : NEG_BIG;
      }
    }
    for (int ct = 0; ct < 4; ct++)
      for (int r = 0; r < 4; r++) {
        float p = __builtin_amdgcn_exp2f(sB[ct][r]);
        lB[r] += p;
        Ps[wv][1][quad * 4 + r][ct * 16 + l16] = f2b(p);
      }
    if (doA)
      for (int ct = 0; ct < 4; ct++)
        for (int r = 0; r < 4; r++) {
          float p = __builtin_amdgcn_exp2f(sA[ct][r]);
          lA[r] += p;
          Ps[wv][0][quad * 4 + r][ct * 16 + l16] = f2b(p);
        }
    bf16x8 apB0 = *(const bf16x8*)&Ps[wv][1][l16][quad * 8];
    bf16x8 apB1 = *(const bf16x8*)&Ps[wv][1][l16][32 + quad * 8];
    bf16x8 apA0, apA1;
    if (doA) {
      apA0 = *(const bf16x8*)&Ps[wv][0][l16][quad * 8];
      apA1 = *(const bf16x8*)&Ps[wv][0][l16][32 + quad * 8];
    }
    for (int ct = 0; ct < 4; ct++) {
      bf16x8 vb0 = *(const bf16x8*)&Vs[ct * 16 + l16][quad * 8];
      bf16x8 vb1 = *(const bf16x8*)&Vs[ct * 16 + l16][32 + quad * 8];
      oB[ct] = __builtin_amdgcn_mfma_f32_16x16x32_bf16(apB0, vb0, oB[ct], 0, 0, 0);
      oB[ct] = __builtin_amdgcn_mfma_f32_16x16x32_bf16(apB1, vb1, oB[ct], 0, 0, 0);
      if (doA) {
        oA[ct] = __builtin_amdgcn_mfma_f32_16x16x32_bf16(apA0, vb0, oA[ct], 0, 0, 0);
        oA[ct] = __builtin_amdgcn_mfma_f32_16x16x32_bf16(apA1, vb1, oA[ct], 0, 0, 0);
      }
    }
  }
  for (int off = 1; off < 16; off <<= 1)
    for (int r = 0; r < 4; r++) {
      lA[r] += __shfl_xor(lA[r], off, 64);
      lB[r] += __shfl_xor(lB[r], off, 64);
    }
  uint16_t* yb = Y + (size_t)b * NS * ND + (size_t)h * NHS;
  for (int ct = 0; ct < 4; ct++)
    for (int r = 0; r < 4; r++) {
      int sA_ = ta * 64 + wv * 16 + quad * 4 + r;
      int sB_ = tb * 64 + wv * 16 + quad * 4 + r;
      yb[(size_t)sA_ * ND + ct * 16 + l16] = f2b(oA[ct][r] / lA[r]);
      yb[(size_t)sB_ * ND + ct * 16 + l16] = f2b(oB[ct][r] / lB[r]);
    }
}
#endif

// ---------------- kernel 3: output projection + bias, m97-style single-phase ----------
// (round-13 verified with k_qkv; keep)
__global__ __launch_bounds__(512, 4) void k_proj(
    const uint16_t* __restrict__ y, const uint16_t* __restrict__ wot,
    const float* __restrict__ bo, float* __restrict__ out) {
  __shared__ __align__(16) uint16_t L[32768];   // 2 bufs x {A 8192, B 8192} u16

  int bid = blockIdx.x;
  int xcd = bid & 7, idx = bid >> 3;     // 64 tiles per XCD chunk
  int mtile = xcd * 8 + (idx & 7);       // 8 m-tiles per XCD, inner
  int ntile = idx >> 3;                  // 8 n-tiles, outer
  int m0 = mtile * 128;
  int n0 = ntile * 128;

  int tid = threadIdx.x;
  int wave = tid >> 6, lane = tid & 63, quad = lane >> 4, l16 = lane & 15;
  int wr = wave >> 2, wc = wave & 3;

  int swc = ((tid & 7) ^ ((tid >> 3) & 7)) * 8;
  const uint16_t* pA = y + (size_t)(m0 + (tid >> 3)) * ND + swc;
  const uint16_t* pB = wot + (size_t)(n0 + (tid >> 3)) * ND + swc;
  const int stOff = wave * 512;

  int e3 = l16 & 7;
  const int rowA = (wr * 64 + l16) * 64;
  const int rowB = 8192 + (wc * 32 + l16) * 64;
  const int ck0 = (quad ^ e3) * 8;
  const int ck1 = ((4 | quad) ^ e3) * 8;

  floatx4 acc[4][2];
  #pragma unroll
  for (int i = 0; i < 4; i++)
    #pragma unroll
    for (int j = 0; j < 2; j++) acc[i][j] = (floatx4){0.f, 0.f, 0.f, 0.f};

#define STAGE_T(T, BUF)                                                         \
  do {                                                                          \
    int kb_ = (T) * 64;                                                         \
    int lb_ = (BUF) * 16384;                                                    \
    gll16(pA + kb_, &L[lb_ + stOff]);                                           \
    gll16(pA + 64 * ND + kb_, &L[lb_ + 4096 + stOff]);                          \
    gll16(pB + kb_, &L[lb_ + 8192 + stOff]);                                    \
    gll16(pB + 64 * ND + kb_, &L[lb_ + 12288 + stOff]);                         \
  } while (0)

#define MFMA8()                                                                           \
  _Pragma("unroll")                                                                       \
  for (int mt_ = 0; mt_ < 4; mt_++)                                                       \
    _Pragma("unroll")                                                                     \
    for (int nt_ = 0; nt_ < 2; nt_++)                                                     \
      acc[mt_][nt_] = __builtin_amdgcn_mfma_f32_16x16x32_bf16(af[mt_], bfr[nt_], acc[mt_][nt_], 0, 0, 0)

  STAGE_T(0, 0);
  __syncthreads();

  for (int t = 0; t < 16; ++t) {
    int cur = t & 1;
    if (t < 15) STAGE_T(t + 1, cur ^ 1);
    const int base = cur * 16384;
    {   // kk = 0
      bf16x8 af[4], bfr[2];
      #pragma unroll
      for (int i = 0; i < 4; i++) af[i] = *(const bf16x8*)&L[base + rowA + i * 1024 + ck0];
      #pragma unroll
      for (int j = 0; j < 2; j++) bfr[j] = *(const bf16x8*)&L[base + rowB + j * 1024 + ck0];
      __builtin_amdgcn_s_setprio(1);
      MFMA8();
      __builtin_amdgcn_s_setprio(0);
    }
    {   // kk = 1
      bf16x8 af[4], bfr[2];
      #pragma unroll
      for (int i = 0; i < 4; i++) af[i] = *(const bf16x8*)&L[base + rowA + i * 1024 + ck1];
      #pragma unroll
      for (int j = 0; j < 2; j++) bfr[j] = *(const bf16x8*)&L[base + rowB + j * 1024 + ck1];
      __builtin_amdgcn_s_setprio(1);
      MFMA8();
      __builtin_amdgcn_s_setprio(0);
    }
    if (t < 15) __syncthreads();
  }
#undef MFMA8
#undef STAGE_T

  // epilogue: fp32 out + bias (col n = n0 + wc*32 + nt*16 + l16)
  float bv[2];
  #pragma unroll
  for (int nt = 0; nt < 2; nt++) bv[nt] = bo[n0 + wc * 32 + nt * 16 + l16];
  #pragma unroll
  for (int mt = 0; mt < 4; mt++) {
    int s = m0 + wr * 64 + mt * 16 + quad * 4;
    #pragma unroll
    for (int nt = 0; nt < 2; nt++) {
      int n = n0 + wc * 32 + nt * 16 + l16;
      #pragma unroll
      for (int r = 0; r < 4; r++)
        out[(size_t)(s + r) * ND + n] = acc[mt][nt][r] + bv[nt];
    }
  }
}

extern "C" void kernel_launch(void* const* d_in, const int* in_sizes, int n_in,
                              void* d_out, int out_size, void* d_ws, size_t ws_size,
                              hipStream_t stream) {
  const float* x  = (const float*)d_in[0];
  const float* Wq = (const float*)d_in[1];
  const float* Wk = (const float*)d_in[2];
  const float* Wv = (const float*)d_in[3];
  const float* Wo = (const float*)d_in[4];
  const float* bo = (const float*)d_in[5];
  uint16_t* ws = (uint16_t*)d_ws;

  uint16_t* wt = ws;                       // 4 * WSLAB bf16 (Wq_t, Wk_t, Wv_t, Wo_t)
  uint16_t* xb = ws + 4 * WSLAB;           // XSLAB bf16
  uint16_t* q  = xb + XSLAB;               // QSLAB each; k contiguous after q
  uint16_t* k  = q + QSLAB;
  uint16_t* vt = k + QSLAB;                // QSLAB (V transposed, written by k_qkv)
  uint16_t* y  = vt + QSLAB;

  k_prep<<<dim3(5120), dim3(256), 0, stream>>>(x, Wq, Wk, Wv, Wo, xb, wt);
  k_qkv<<<dim3(1536), dim3(512), 0, stream>>>(xb, wt, q, vt);
  k_attn<<<dim3(1024), dim3(256), 0, stream>>>(q, k, vt, y);
  k_proj<<<dim3(512), dim3(512), 0, stream>>>(y, wt + 3 * WSLAB, bo, (float*)d_out);
}